// Round 13
// baseline (210.044 us; speedup 1.0000x reference)
//
#include <hip/hip_runtime.h>
#include <hip/hip_bf16.h>
#include <math.h>

// Masked dot-product attention, bf16 MFMA flash kernel, round 16.
// B=32, LQ=LK=2048, D=64. S^T = K*Q^T and O^T = V^T*P^T with 32x32x16 MFMA.
// NEW: barrier-free fragment-direct structure.
//  - r12..r15 post-mortem: counters reconcile to ~600 issue-cycles vs ~9.8k
//    wall-cycles per block-tile (94% stall, ~2 blocks/CU effective): the
//    4-wave lockstep + LDS staging structure is latency-bound, and no pipe
//    is >11% busy. Trims moved nothing (3 nulls).
//  - Fix: pre-pass converts K->bf16 and V->bf16 TRANSPOSED (Vtb[b][d][k])
//    once (~50MB, BW-bound). MFMA A-frags then load DIRECTLY from global
//    (16B contiguous, byte-identical to the old swizzled-LDS reads):
//    no LDS, no __syncthreads, no per-tile cvt. 4 INDEPENDENT waves per
//    block (one 32-row q-tile each) self-pack the SIMDs.
//  - launch_bounds (256,4) caps VGPR at 128 (peak live ~112-120).
//  - LPT wave-task order + NS=4 split + proven merge kernel retained.
//  - Fallbacks: r15 split kernel (proven 66us) if ws lacks Kb/Vtb space;
//    mono kernel if no ws.

#define B_    32
#define LQ_   2048
#define LK_   2048
#define D_    64

typedef __attribute__((ext_vector_type(8)))  short bf16x8;
typedef __attribute__((ext_vector_type(4)))  float f32x4;
typedef __attribute__((ext_vector_type(16))) float f32x16;
typedef __attribute__((ext_vector_type(2)))  unsigned u32x2;

static __device__ __forceinline__ unsigned pk_bf16(float a, float b) {
    __hip_bfloat162 h = __float22bfloat162_rn(float2{a, b});
    return *(unsigned*)&h;   // x in low 16 bits, y in high
}

static __device__ __forceinline__ u32x2 plswap(unsigned a, unsigned b) {
    return __builtin_amdgcn_permlane32_swap(a, b, false, false);
}
static __device__ __forceinline__ float xhalf_max(float x) {
    u32x2 r = plswap(__float_as_uint(x), __float_as_uint(x));
    return fmaxf(__uint_as_float(r[0]), __uint_as_float(r[1]));
}
static __device__ __forceinline__ float xhalf_add(float x) {
    u32x2 r = plswap(__float_as_uint(x), __float_as_uint(x));
    return __uint_as_float(r[0]) + __uint_as_float(r[1]);
}

// ---------------------------------------------------------------------------
// Pass 0: K (f32 [b][k][d]) -> Kb (bf16 [b][k][d]);
//         V (f32 [b][k][d]) -> Vtb (bf16 [b][d][k])  (transposed).
// Grid: (32 key-tiles, 32 batches) x 256 threads. BW-bound (~50 MB).
// ---------------------------------------------------------------------------
__global__ __launch_bounds__(256) void fa_cvt_kernel(
    const float* __restrict__ K, const float* __restrict__ V,
    short* __restrict__ Kb, short* __restrict__ Vtb)
{
    const int tid = threadIdx.x;
    const int b   = blockIdx.y;
    const int k0  = blockIdx.x * 64;

    // ---- K copy-convert: thread row kk (0..63), quarter q4 (0..3) ----
    {
        const int kk = tid >> 2, q4 = tid & 3;
        const size_t off = ((size_t)(b * LK_ + k0 + kk)) * D_ + q4 * 16;
        const float* src = K + off;
        unsigned w[8];
#pragma unroll
        for (int i = 0; i < 4; ++i) {
            f32x4 v = *(const f32x4*)(src + 4 * i);
            w[2 * i]     = pk_bf16(v[0], v[1]);
            w[2 * i + 1] = pk_bf16(v[2], v[3]);
        }
        short* dst = Kb + off;
        *(bf16x8*)dst       = *(bf16x8*)&w[0];
        *(bf16x8*)(dst + 8) = *(bf16x8*)&w[4];
    }
    // ---- V transpose-convert: thread keygroup vkg (0..15), dimgroup vdg ----
    {
        const int vkg = tid & 15, vdg = tid >> 4;
        f32x4 vv[4];
#pragma unroll
        for (int p = 0; p < 4; ++p)
            vv[p] = *(const f32x4*)&V[((size_t)(b * LK_ + k0 + vkg * 4 + p)) * D_ + vdg * 4];
#pragma unroll
        for (int dr = 0; dr < 4; ++dr) {
            uint2 w = { pk_bf16(vv[0][dr], vv[1][dr]), pk_bf16(vv[2][dr], vv[3][dr]) };
            *(uint2*)&Vtb[((size_t)(b * 64 + vdg * 4 + dr)) * LK_ + k0 + vkg * 4] = w;
        }
    }
}

// ---------------------------------------------------------------------------
// Pass 1: barrier-free fragment-direct flash attention.
// 256 threads = 4 INDEPENDENT waves; wave-task T = blockIdx*4+wid ->
// (batch_rank, q-tile of 32 rows, split). LPT rank via shfl+ballot.
// Writes UNNORMALIZED O^T partial + (m, l) per q row.
// ---------------------------------------------------------------------------
template<int NS>
__global__ __launch_bounds__(256, 4) void fa_frag_kernel(
    const float* __restrict__ Q, const short* __restrict__ Kb,
    const short* __restrict__ Vtb, const int* __restrict__ vlen,
    float* __restrict__ OP, float* __restrict__ ML)
{
    const int tid  = threadIdx.x;          // 0..255
    const int wid  = tid >> 6;             // independent wave id
    const int lane = tid & 63;
    const int c31  = lane & 31;
    const int h    = lane >> 5;

    // ---- LPT wave-task remap ----
    constexpr int PB = 64 * NS;            // wave-tasks per batch
    const int T    = blockIdx.x * 4 + wid;
    const int rank = T / PB;
    const int sub  = T % PB;
    const int qw   = sub & 63;
    const int s    = sub >> 6;
    int b;
    {
        const int vj = vlen[c31];          // lanes j and j+32 hold vlen[j]
        int r = 0;
#pragma unroll
        for (int k = 0; k < 32; ++k) {
            const int vk = __shfl(vj, k);
            r += (vk > vj) || (vk == vj && k < c31);
        }
        const unsigned long long match = __ballot(r == rank);
        b = (int)(__ffsll(match) - 1) & 31;
    }
    const int q0 = qw * 32;
    const int vl = vlen[b];
    const int nt    = (vl + 63) >> 6;
    const int chunk = (nt + NS - 1) / NS;
    const int t0    = s * chunk;
    const int t1    = min(t0 + chunk, nt);

    const float qscale = 0.125f * 1.44269504088896340736f;  // 1/sqrt(64)*log2(e)

    // ---- Q B-frags: B[k=dim][n=q], dim = ks*16 + h*8 + j ----
    unsigned qfrag[4][4];
#pragma unroll
    for (int ks = 0; ks < 4; ++ks) {
        const float* qp = Q + ((size_t)(b * LQ_ + q0 + c31)) * D_ + ks * 16 + h * 8;
        f32x4 t0v = *(const f32x4*)qp;
        f32x4 t1v = *(const f32x4*)(qp + 4);
#pragma unroll
        for (int jj = 0; jj < 2; ++jj) {
            qfrag[ks][jj]     = pk_bf16(t0v[2*jj] * qscale, t0v[2*jj+1] * qscale);
            qfrag[ks][jj + 2] = pk_bf16(t1v[2*jj] * qscale, t1v[2*jj+1] * qscale);
        }
    }

    f32x16 oacc[2];     // O^T acc: dim row = dt*32 + (r&3)+8*(r>>2)+4h, col q = c31
#pragma unroll
    for (int dt = 0; dt < 2; ++dt)
#pragma unroll
        for (int r = 0; r < 16; ++r) oacc[dt][r] = 0.f;
    float mrun = -INFINITY, lrun = 0.f;

    const short* kb  = Kb  + (size_t)b * LK_ * D_;
    const short* vtb = Vtb + (size_t)b * D_ * LK_;

    for (int t = t0; t < t1; ++t) {
        const int k0 = t * 64;

        // ---- K A-frags direct from global: row = k0+ss*32+c31, dims ks*16+h*8 ----
        bf16x8 kf[2][4];
#pragma unroll
        for (int ss = 0; ss < 2; ++ss)
#pragma unroll
            for (int ks = 0; ks < 4; ++ks)
                kf[ss][ks] = *(const bf16x8*)&kb[((size_t)(k0 + ss * 32 + c31)) * D_ + ks * 16 + h * 8];

        // ---- S^T = K * Q^T ----
        f32x16 st[2];
#pragma unroll
        for (int ss = 0; ss < 2; ++ss) {
#pragma unroll
            for (int r = 0; r < 16; ++r) st[ss][r] = 0.f;
#pragma unroll
            for (int ks = 0; ks < 4; ++ks)
                st[ss] = __builtin_amdgcn_mfma_f32_32x32x16_bf16(
                    kf[ss][ks], *(const bf16x8*)&qfrag[ks][0], st[ss], 0, 0, 0);
        }

        // ---- V A-frags direct from global: row dim = dt*32+c31, keys kq*16+h*8 ----
        //      (issued here so the loads fly under the softmax below)
        bf16x8 vf[2][4];
#pragma unroll
        for (int dt = 0; dt < 2; ++dt)
#pragma unroll
            for (int kq = 0; kq < 4; ++kq)
                vf[dt][kq] = *(const bf16x8*)&vtb[((size_t)(dt * 32 + c31)) * LK_ + k0 + kq * 16 + h * 8];

        // ---- mask tail keys >= vl ----
        if (k0 + 64 > vl) {
#pragma unroll
            for (int ss = 0; ss < 2; ++ss) {
                const int base = k0 + ss * 32 + 4 * h;
#pragma unroll
                for (int r = 0; r < 16; ++r) {
                    const int key = base + (r & 3) + 8 * (r >> 2);
                    if (key >= vl) st[ss][r] = -1e30f;
                }
            }
        }

        // ---- online softmax (log2 domain), defer-max; tree reductions ----
        float m8[8];
#pragma unroll
        for (int r = 0; r < 8; ++r)
            m8[r] = fmaxf(fmaxf(st[0][r], st[0][r + 8]),
                          fmaxf(st[1][r], st[1][r + 8]));
#pragma unroll
        for (int o = 4; o; o >>= 1)
#pragma unroll
            for (int r = 0; r < o; ++r) m8[r] = fmaxf(m8[r], m8[r + o]);
        const float tm = xhalf_max(m8[0]);

        if (__any(tm > mrun + 8.f)) {          // rare after the first tile
            const float mnew = fmaxf(mrun, tm);
            const float corr = exp2f(mrun - mnew);
            lrun *= corr;
#pragma unroll
            for (int dt = 0; dt < 2; ++dt)
#pragma unroll
                for (int r = 0; r < 16; ++r) oacc[dt][r] *= corr;
            mrun = mnew;
        }
#pragma unroll
        for (int ss = 0; ss < 2; ++ss)
#pragma unroll
            for (int r = 0; r < 16; ++r)
                st[ss][r] = exp2f(st[ss][r] - mrun);   // bounded by 2^8
        float s8[8];
#pragma unroll
        for (int r = 0; r < 8; ++r)
            s8[r] = (st[0][r] + st[0][r + 8]) + (st[1][r] + st[1][r + 8]);
#pragma unroll
        for (int o = 4; o; o >>= 1)
#pragma unroll
            for (int r = 0; r < o; ++r) s8[r] += s8[r + o];
        lrun += xhalf_add(s8[0]);

        // ---- pack P to bf16 pairs ----
        unsigned pk[2][8];
#pragma unroll
        for (int ss = 0; ss < 2; ++ss)
#pragma unroll
            for (int m = 0; m < 8; ++m)
                pk[ss][m] = pk_bf16(st[ss][2 * m], st[ss][2 * m + 1]);

        // ---- O^T += V^T * P^T ----
#pragma unroll
        for (int kq = 0; kq < 4; ++kq) {
            const int ss = kq >> 1, A4 = (kq & 1) * 4;
            u32x2 r02 = plswap(pk[ss][A4],     pk[ss][A4 + 2]);
            u32x2 r13 = plswap(pk[ss][A4 + 1], pk[ss][A4 + 3]);
            unsigned pf[4] = {r02[0], r13[0], r02[1], r13[1]};
            const bf16x8 pfr = *(const bf16x8*)&pf[0];
#pragma unroll
            for (int dt = 0; dt < 2; ++dt)
                oacc[dt] = __builtin_amdgcn_mfma_f32_32x32x16_bf16(
                    vf[dt][kq], pfr, oacc[dt], 0, 0, 0);
        }
    }

    // ---- epilogue: store UNNORMALIZED partial O^T and (m, l) ----
    const size_t row = (size_t)s * (B_ * LQ_) + b * LQ_ + q0 + c31;
    float* op = OP + row * D_;
#pragma unroll
    for (int dt = 0; dt < 2; ++dt)
#pragma unroll
        for (int g = 0; g < 4; ++g) {
            f32x4 v;
#pragma unroll
            for (int j = 0; j < 4; ++j) v[j] = oacc[dt][4 * g + j];
            *(f32x4*)(op + dt * 32 + 8 * g + 4 * h) = v;
        }
    if (h == 0)
        *(float2*)&ML[row * 2] = float2{mrun, lrun};   // (-inf, 0) if empty split
}

// ---------------------------------------------------------------------------
// Pass 2: merge NS partials per q row. One thread per (row, 4-dim chunk).
// ---------------------------------------------------------------------------
template<int NS>
__global__ __launch_bounds__(256) void fa_merge_kernel(
    const float* __restrict__ OP, const float* __restrict__ ML,
    float* __restrict__ O)
{
    const int g   = blockIdx.x * 256 + threadIdx.x;   // 0 .. B*LQ*16-1
    const int row = g >> 4;                            // b*LQ + q
    const int qd  = (g & 15) * 4;

    float mf = -INFINITY;
#pragma unroll
    for (int s = 0; s < NS; ++s) {
        float2 ml = *(const float2*)&ML[((size_t)s * (B_ * LQ_) + row) * 2];
        mf = fmaxf(mf, ml.x);                          // split 0 always finite
    }
    float den = 0.f;
    f32x4 acc = {0.f, 0.f, 0.f, 0.f};
#pragma unroll
    for (int s = 0; s < NS; ++s) {
        const size_t srow = (size_t)s * (B_ * LQ_) + row;
        float2 ml = *(const float2*)&ML[srow * 2];
        const float c = exp2f(ml.x - mf);              // 0 for empty splits
        den += c * ml.y;
        f32x4 v = *(const f32x4*)&OP[srow * D_ + qd];
        acc += v * c;                                  // empty split: c=0, v=0
    }
    const float inv = 1.f / den;
    *(f32x4*)(O + (size_t)row * D_ + qd) = acc * inv;
}

// ---------------------------------------------------------------------------
// Fallback A: r15 LDS-staged split kernel (proven, 66us). Used when the
// workspace can hold partials but not Kb/Vtb.
// ---------------------------------------------------------------------------
template<int NS>
__global__ __launch_bounds__(256, 2) void fa_split9_kernel(
    const float* __restrict__ Q, const float* __restrict__ K,
    const float* __restrict__ V, const int* __restrict__ vlen,
    float* __restrict__ OP, float* __restrict__ ML)
{
    __shared__ __align__(16) short Kl[2][64 * 64];
    __shared__ __align__(16) short Vt[2][64 * 64];

    const int tid  = threadIdx.x;
    const int wid  = tid >> 6;
    const int lane = tid & 63;
    const int c31  = lane & 31;
    const int h    = lane >> 5;

    constexpr int PB = 16 * NS;
    const int L    = blockIdx.x;
    const int rank = L / PB;
    const int sub  = L % PB;
    const int qb   = sub & 15;
    const int s    = sub >> 4;
    int b;
    {
        const int vj = vlen[c31];
        int r = 0;
#pragma unroll
        for (int k = 0; k < 32; ++k) {
            const int vk = __shfl(vj, k);
            r += (vk > vj) || (vk == vj && k < c31);
        }
        const unsigned long long match = __ballot(r == rank);
        b = (int)(__ffsll(match) - 1) & 31;
    }
    const int q0 = qb * 128 + wid * 32;
    const int vl = vlen[b];
    const int nt    = (vl + 63) >> 6;
    const int chunk = (nt + NS - 1) / NS;
    const int t0    = s * chunk;
    const int t1    = min(t0 + chunk, nt);

    const float qscale = 0.125f * 1.44269504088896340736f;

    unsigned qfrag[4][4];
#pragma unroll
    for (int ks = 0; ks < 4; ++ks) {
        const float* qp = Q + ((size_t)(b * LQ_ + q0 + c31)) * D_ + ks * 16 + h * 8;
        f32x4 t0v = *(const f32x4*)qp;
        f32x4 t1v = *(const f32x4*)(qp + 4);
#pragma unroll
        for (int jj = 0; jj < 2; ++jj) {
            qfrag[ks][jj]     = pk_bf16(t0v[2*jj] * qscale, t0v[2*jj+1] * qscale);
            qfrag[ks][jj + 2] = pk_bf16(t1v[2*jj] * qscale, t1v[2*jj+1] * qscale);
        }
    }

    f32x16 oacc[2];
#pragma unroll
    for (int dt = 0; dt < 2; ++dt)
#pragma unroll
        for (int r = 0; r < 16; ++r) oacc[dt][r] = 0.f;
    float mrun = -INFINITY, lrun = 0.f;

    const int skey = tid >> 2, skh = tid & 3;
    const int vkg = tid >> 4, vdg = tid & 15;

    const float* kgp = K + ((size_t)(b * LK_ + skey)) * D_ + skh * 16;
    const float* vgp = V + ((size_t)(b * LK_ + vkg * 4)) * D_ + vdg * 4;

    f32x4 kr[4], vr[4];
    if (t0 < t1) {
        const size_t off = (size_t)t0 * 64 * D_;
#pragma unroll
        for (int i = 0; i < 4; ++i) kr[i] = *(const f32x4*)(kgp + off + 4 * i);
#pragma unroll
        for (int i = 0; i < 4; ++i) vr[i] = *(const f32x4*)(vgp + off + (size_t)i * D_);
    }

    for (int t = t0; t < t1; ++t) {
        const int k0 = t * 64;
        const int buf = t & 1;
        {
            unsigned pk32[8];
#pragma unroll
            for (int m = 0; m < 8; ++m)
                pk32[m] = pk_bf16(kr[m >> 1][2 * (m & 1)], kr[m >> 1][2 * (m & 1) + 1]);
#pragma unroll
            for (int cch = 0; cch < 2; ++cch) {
                const int pos = (skh * 2 + cch) ^ (skey & 7);
                *(bf16x8*)&Kl[buf][skey * 64 + pos * 8] = *(bf16x8*)&pk32[4 * cch];
            }
#pragma unroll
            for (int dr = 0; dr < 4; ++dr) {
                const unsigned w0 = pk_bf16(vr[0][dr], vr[1][dr]);
                const unsigned w1 = pk_bf16(vr[2][dr], vr[3][dr]);
                const int dim = vdg * 4 + dr;
                const int pos = (vkg >> 1) ^ (dim & 7);
                *(uint2*)&Vt[buf][dim * 64 + pos * 8 + (vkg & 1) * 4] = uint2{w0, w1};
            }
        }
        __syncthreads();
        if (t + 1 < t1) {
            const float* kn = kgp + (size_t)(k0 + 64) * D_;
            const float* vn = vgp + (size_t)(k0 + 64) * D_;
#pragma unroll
            for (int i = 0; i < 4; ++i) kr[i] = *(const f32x4*)(kn + 4 * i);
#pragma unroll
            for (int i = 0; i < 4; ++i) vr[i] = *(const f32x4*)(vn + (size_t)i * D_);
        }

        f32x16 st[2];
#pragma unroll
        for (int ss = 0; ss < 2; ++ss) {
#pragma unroll
            for (int r = 0; r < 16; ++r) st[ss][r] = 0.f;
#pragma unroll
            for (int ks = 0; ks < 4; ++ks) {
                const int pos = (ks * 2 + h) ^ (c31 & 7);
                bf16x8 kf = *(const bf16x8*)&Kl[buf][(ss * 32 + c31) * 64 + pos * 8];
                st[ss] = __builtin_amdgcn_mfma_f32_32x32x16_bf16(
                    kf, *(const bf16x8*)&qfrag[ks][0], st[ss], 0, 0, 0);
            }
        }
        if (k0 + 64 > vl) {
#pragma unroll
            for (int ss = 0; ss < 2; ++ss) {
                const int base = k0 + ss * 32 + 4 * h;
#pragma unroll
                for (int r = 0; r < 16; ++r) {
                    const int key = base + (r & 3) + 8 * (r >> 2);
                    if (key >= vl) st[ss][r] = -1e30f;
                }
            }
        }
        float m8[8];
#pragma unroll
        for (int r = 0; r < 8; ++r)
            m8[r] = fmaxf(fmaxf(st[0][r], st[0][r + 8]),
                          fmaxf(st[1][r], st[1][r + 8]));
#pragma unroll
        for (int o = 4; o; o >>= 1)
#pragma unroll
            for (int r = 0; r < o; ++r) m8[r] = fmaxf(m8[r], m8[r + o]);
        const float tm = xhalf_max(m8[0]);
        if (__any(tm > mrun + 8.f)) {
            const float mnew = fmaxf(mrun, tm);
            const float corr = exp2f(mrun - mnew);
            lrun *= corr;
#pragma unroll
            for (int dt = 0; dt < 2; ++dt)
#pragma unroll
                for (int r = 0; r < 16; ++r) oacc[dt][r] *= corr;
            mrun = mnew;
        }
#pragma unroll
        for (int ss = 0; ss < 2; ++ss)
#pragma unroll
            for (int r = 0; r < 16; ++r)
                st[ss][r] = exp2f(st[ss][r] - mrun);
        float s8[8];
#pragma unroll
        for (int r = 0; r < 8; ++r)
            s8[r] = (st[0][r] + st[0][r + 8]) + (st[1][r] + st[1][r + 8]);
#pragma unroll
        for (int o = 4; o; o >>= 1)
#pragma unroll
            for (int r = 0; r < o; ++r) s8[r] += s8[r + o];
        lrun += xhalf_add(s8[0]);

        unsigned pk[2][8];
#pragma unroll
        for (int ss = 0; ss < 2; ++ss)
#pragma unroll
            for (int m = 0; m < 8; ++m)
                pk[ss][m] = pk_bf16(st[ss][2 * m], st[ss][2 * m + 1]);
#pragma unroll
        for (int kq = 0; kq < 4; ++kq) {
            const int ss = kq >> 1, A4 = (kq & 1) * 4;
            u32x2 r02 = plswap(pk[ss][A4],     pk[ss][A4 + 2]);
            u32x2 r13 = plswap(pk[ss][A4 + 1], pk[ss][A4 + 3]);
            unsigned pf[4] = {r02[0], r13[0], r02[1], r13[1]};
            const bf16x8 pfr = *(const bf16x8*)&pf[0];
#pragma unroll
            for (int dt = 0; dt < 2; ++dt) {
                const int pos = (kq * 2 + h) ^ (c31 & 7);
                bf16x8 vfv = *(const bf16x8*)&Vt[buf][(dt * 32 + c31) * 64 + pos * 8];
                oacc[dt] = __builtin_amdgcn_mfma_f32_32x32x16_bf16(vfv, pfr, oacc[dt], 0, 0, 0);
            }
        }
    }

    const size_t row = (size_t)s * (B_ * LQ_) + b * LQ_ + q0 + c31;
    float* op = OP + row * D_;
#pragma unroll
    for (int dt = 0; dt < 2; ++dt)
#pragma unroll
        for (int g = 0; g < 4; ++g) {
            f32x4 v;
#pragma unroll
            for (int j = 0; j < 4; ++j) v[j] = oacc[dt][4 * g + j];
            *(f32x4*)(op + dt * 32 + 8 * g + 4 * h) = v;
        }
    if (h == 0)
        *(float2*)&ML[row * 2] = float2{mrun, lrun};
}

// ---------------------------------------------------------------------------
// Fallback B: monolithic kernel, no workspace.
// ---------------------------------------------------------------------------
__global__ __launch_bounds__(128, 2) void fa_mono_kernel(
    const float* __restrict__ Q, const float* __restrict__ K,
    const float* __restrict__ V, const int* __restrict__ vlen,
    float* __restrict__ O)
{
    __shared__ __align__(16) short Kl[2][64 * 64];
    __shared__ __align__(16) short Vt[2][64 * 64];

    const int tid  = threadIdx.x;
    const int wave = tid >> 6;
    const int lane = tid & 63;
    const int c31  = lane & 31;
    const int h    = lane >> 5;

    const int b  = blockIdx.y;
    const int q0 = blockIdx.x * 64 + wave * 32;
    const int vl = vlen[b];
    const int nt = (vl + 63) >> 6;

    const float qscale = 0.125f * 1.44269504088896340736f;

    unsigned qfrag[4][4];
#pragma unroll
    for (int ks = 0; ks < 4; ++ks) {
        const float* qp = Q + ((size_t)(b * LQ_ + q0 + c31)) * D_ + ks * 16 + h * 8;
        f32x4 t0 = *(const f32x4*)qp;
        f32x4 t1 = *(const f32x4*)(qp + 4);
#pragma unroll
        for (int jj = 0; jj < 2; ++jj) {
            qfrag[ks][jj]     = pk_bf16(t0[2*jj] * qscale, t0[2*jj+1] * qscale);
            qfrag[ks][jj + 2] = pk_bf16(t1[2*jj] * qscale, t1[2*jj+1] * qscale);
        }
    }

    f32x16 oacc[2];
#pragma unroll
    for (int dt = 0; dt < 2; ++dt)
#pragma unroll
        for (int r = 0; r < 16; ++r) oacc[dt][r] = 0.f;
    float mrun = -INFINITY, lrun = 0.f;

    const int skey = tid >> 1, skh = tid & 1;
    const int vkg = tid >> 4, vdg = tid & 15;

    const float* kgp = K + ((size_t)(b * LK_ + skey)) * D_ + skh * 32;
    const float* vgp = V + ((size_t)(b * LK_ + vkg * 8)) * D_ + vdg * 4;

    f32x4 kr[8], vr[8];
#pragma unroll
    for (int i = 0; i < 8; ++i) kr[i] = *(const f32x4*)(kgp + 4 * i);
#pragma unroll
    for (int i = 0; i < 8; ++i) vr[i] = *(const f32x4*)(vgp + (size_t)i * D_);

    for (int t = 0; t < nt; ++t) {
        const int k0 = t * 64;
        const int buf = t & 1;
        {
            unsigned pk32[16];
#pragma unroll
            for (int m = 0; m < 16; ++m)
                pk32[m] = pk_bf16(kr[m >> 1][2 * (m & 1)], kr[m >> 1][2 * (m & 1) + 1]);
#pragma unroll
            for (int cch = 0; cch < 4; ++cch) {
                const int pos = (skh * 4 + cch) ^ (skey & 7);
                *(bf16x8*)&Kl[buf][skey * 64 + pos * 8] = *(bf16x8*)&pk32[4 * cch];
            }
#pragma unroll
            for (int dr = 0; dr < 4; ++dr) {
                unsigned w[4];
#pragma unroll
                for (int p = 0; p < 4; ++p)
                    w[p] = pk_bf16(vr[2 * p][dr], vr[2 * p + 1][dr]);
                const int dim = vdg * 4 + dr;
                const int pos = vkg ^ (dim & 7);
                *(bf16x8*)&Vt[buf][dim * 64 + pos * 8] = *(bf16x8*)&w[0];
            }
        }
        if (t + 1 < nt) {
            const float* kn = kgp + (size_t)(k0 + 64) * D_;
            const float* vn = vgp + (size_t)(k0 + 64) * D_;
#pragma unroll
            for (int i = 0; i < 8; ++i) kr[i] = *(const f32x4*)(kn + 4 * i);
#pragma unroll
            for (int i = 0; i < 8; ++i) vr[i] = *(const f32x4*)(vn + (size_t)i * D_);
        }
        __syncthreads();

        f32x16 st[2];
#pragma unroll
        for (int ss = 0; ss < 2; ++ss) {
#pragma unroll
            for (int r = 0; r < 16; ++r) st[ss][r] = 0.f;
#pragma unroll
            for (int ks = 0; ks < 4; ++ks) {
                const int pos = (ks * 2 + h) ^ (c31 & 7);
                bf16x8 kf = *(const bf16x8*)&Kl[buf][(ss * 32 + c31) * 64 + pos * 8];
                st[ss] = __builtin_amdgcn_mfma_f32_32x32x16_bf16(
                    kf, *(const bf16x8*)&qfrag[ks][0], st[ss], 0, 0, 0);
            }
        }
        if (k0 + 64 > vl) {
#pragma unroll
            for (int ss = 0; ss < 2; ++ss) {
                const int base = k0 + ss * 32 + 4 * h;
#pragma unroll
                for (int r = 0; r < 16; ++r) {
                    const int key = base + (r & 3) + 8 * (r >> 2);
                    if (key >= vl) st[ss][r] = -1e30f;
                }
            }
        }
        float tm = st[0][0];
#pragma unroll
        for (int ss = 0; ss < 2; ++ss)
#pragma unroll
            for (int r = 0; r < 16; ++r) tm = fmaxf(tm, st[ss][r]);
        tm = fmaxf(tm, __shfl_xor(tm, 32));
        if (__any(tm > mrun + 8.f)) {
            const float mnew = fmaxf(mrun, tm);
            const float corr = exp2f(mrun - mnew);
            lrun *= corr;
#pragma unroll
            for (int dt = 0; dt < 2; ++dt)
#pragma unroll
                for (int r = 0; r < 16; ++r) oacc[dt][r] *= corr;
            mrun = mnew;
        }
        float rs = 0.f;
#pragma unroll
        for (int ss = 0; ss < 2; ++ss)
#pragma unroll
            for (int r = 0; r < 16; ++r) {
                const float p = exp2f(st[ss][r] - mrun);
                st[ss][r] = p;
                rs += p;
            }
        rs += __shfl_xor(rs, 32);
        lrun += rs;

        unsigned pk[2][8];
#pragma unroll
        for (int ss = 0; ss < 2; ++ss)
#pragma unroll
            for (int m = 0; m < 8; ++m)
                pk[ss][m] = pk_bf16(st[ss][2 * m], st[ss][2 * m + 1]);
#pragma unroll
        for (int kq = 0; kq < 4; ++kq) {
            const int ss = kq >> 1, A4 = (kq & 1) * 4;
            unsigned p0 = pk[ss][A4], p1 = pk[ss][A4+1], p2 = pk[ss][A4+2], p3 = pk[ss][A4+3];
            unsigned xp0 = __shfl_xor((int)p0, 32);
            unsigned xp1 = __shfl_xor((int)p1, 32);
            unsigned xp2 = __shfl_xor((int)p2, 32);
            unsigned xp3 = __shfl_xor((int)p3, 32);
            unsigned pf[4];
            pf[0] = h ? xp2 : p0;
            pf[1] = h ? xp3 : p1;
            pf[2] = h ? p2  : xp0;
            pf[3] = h ? p3  : xp1;
            const bf16x8 pfr = *(const bf16x8*)&pf[0];
#pragma unroll
            for (int dt = 0; dt < 2; ++dt) {
                const int pos = (kq * 2 + h) ^ (c31 & 7);
                bf16x8 vf = *(const bf16x8*)&Vt[buf][(dt * 32 + c31) * 64 + pos * 8];
                oacc[dt] = __builtin_amdgcn_mfma_f32_32x32x16_bf16(vf, pfr, oacc[dt], 0, 0, 0);
            }
        }
    }

    const float inv = 1.f / lrun;
    float* op = O + ((size_t)(b * LQ_ + q0 + c31)) * D_;
#pragma unroll
    for (int dt = 0; dt < 2; ++dt)
#pragma unroll
        for (int g = 0; g < 4; ++g) {
            f32x4 v;
#pragma unroll
            for (int j = 0; j < 4; ++j) v[j] = oacc[dt][4 * g + j] * inv;
            *(f32x4*)(op + dt * 32 + 8 * g + 4 * h) = v;
        }
}

extern "C" void kernel_launch(void* const* d_in, const int* in_sizes, int n_in,
                              void* d_out, int out_size, void* d_ws, size_t ws_size,
                              hipStream_t stream) {
    const float* Q    = (const float*)d_in[0];
    const float* K    = (const float*)d_in[1];
    const float* V    = (const float*)d_in[2];
    const int*   vlen = (const int*)d_in[3];
    float*       O    = (float*)d_out;

    const size_t rows    = (size_t)B_ * LQ_;
    const size_t kvElems = (size_t)B_ * LK_ * D_;          // per tensor
    auto needP = [&](int ns) { return (size_t)ns * rows * (D_ + 2) * sizeof(float); };
    const size_t needKV = 2 * kvElems * sizeof(short);     // Kb + Vtb (33.6 MB)

    constexpr int NS = 4;

    if (d_ws && ws_size >= needP(NS) + needKV) {
        // ---- fragment-direct path ----
        float* OP  = (float*)d_ws;
        float* ML  = OP + (size_t)NS * rows * D_;
        short* Kb  = (short*)(ML + (size_t)NS * rows * 2);
        short* Vtb = Kb + kvElems;

        fa_cvt_kernel<<<dim3(LK_ / 64, B_), dim3(256), 0, stream>>>(K, V, Kb, Vtb);

        const unsigned nblk = (unsigned)(64 * B_ * NS / 4);   // 2048 blocks, 4 wave-tasks each
        fa_frag_kernel<NS><<<dim3(nblk), dim3(256), 0, stream>>>(Q, Kb, Vtb, vlen, OP, ML);

        dim3 g2((unsigned)((rows * (D_ / 4)) / 256));
        fa_merge_kernel<NS><<<g2, dim3(256), 0, stream>>>(OP, ML, O);
        return;
    }

    if (d_ws && ws_size >= needP(NS)) {
        // ---- r15 LDS-staged path (proven) ----
        float* OP = (float*)d_ws;
        float* ML = OP + (size_t)NS * rows * D_;
        const unsigned nblk = (unsigned)(16 * B_ * NS);
        fa_split9_kernel<NS><<<dim3(nblk), dim3(256), 0, stream>>>(Q, K, V, vlen, OP, ML);
        dim3 g2((unsigned)((rows * (D_ / 4)) / 256));
        fa_merge_kernel<NS><<<g2, dim3(256), 0, stream>>>(OP, ML, O);
        return;
    }

    dim3 grid(LQ_ / 64, B_);
    fa_mono_kernel<<<grid, dim3(128), 0, stream>>>(Q, K, V, vlen, O);
}

// Round 14
// 192.762 us; speedup vs baseline: 1.0897x; 1.0897x over previous
//
#include <hip/hip_runtime.h>
#include <hip/hip_bf16.h>
#include <math.h>

// Masked dot-product attention, bf16 MFMA flash kernel, round 17.
// B=32, LQ=LK=2048, D=64. S^T = K*Q^T and O^T = V^T*P^T with 32x32x16 MFMA.
// = round 16 fragment-direct structure + REGISTER DISCIPLINE (fixes spill).
//  - r16 post-mortem: forcing kf[2][4]+vf[2][4]+st+oacc+qfrag ~150 live regs
//    against the (256,4) 128-cap -> allocator spilled (VGPR=64, WRITE_SIZE
//    67.6->107MB scratch traffic, MfmaUtil 6.1, 115us). Occupancy did rise
//    (36%) and bank conflicts hit 0 -> structure is right, footprint wasn't.
//  - Fix: K-frags loaded per-ss inside QK (16 live, die into MFMA); PV
//    computes all P-frags first (pk dies), then per-dt loads 4 V-frags.
//    Peak live ~110 < 128; allocator hoists loads within budget.
//  - Falsifiable: WRITE_SIZE back to ~67.6MB == spill gone.

#define B_    32
#define LQ_   2048
#define LK_   2048
#define D_    64

typedef __attribute__((ext_vector_type(8)))  short bf16x8;
typedef __attribute__((ext_vector_type(4)))  float f32x4;
typedef __attribute__((ext_vector_type(16))) float f32x16;
typedef __attribute__((ext_vector_type(2)))  unsigned u32x2;

static __device__ __forceinline__ unsigned pk_bf16(float a, float b) {
    __hip_bfloat162 h = __float22bfloat162_rn(float2{a, b});
    return *(unsigned*)&h;   // x in low 16 bits, y in high
}

static __device__ __forceinline__ u32x2 plswap(unsigned a, unsigned b) {
    return __builtin_amdgcn_permlane32_swap(a, b, false, false);
}
static __device__ __forceinline__ float xhalf_max(float x) {
    u32x2 r = plswap(__float_as_uint(x), __float_as_uint(x));
    return fmaxf(__uint_as_float(r[0]), __uint_as_float(r[1]));
}
static __device__ __forceinline__ float xhalf_add(float x) {
    u32x2 r = plswap(__float_as_uint(x), __float_as_uint(x));
    return __uint_as_float(r[0]) + __uint_as_float(r[1]);
}

// ---------------------------------------------------------------------------
// Pass 0: K (f32 [b][k][d]) -> Kb (bf16 [b][k][d]);
//         V (f32 [b][k][d]) -> Vtb (bf16 [b][d][k])  (transposed).
// ---------------------------------------------------------------------------
__global__ __launch_bounds__(256) void fa_cvt_kernel(
    const float* __restrict__ K, const float* __restrict__ V,
    short* __restrict__ Kb, short* __restrict__ Vtb)
{
    const int tid = threadIdx.x;
    const int b   = blockIdx.y;
    const int k0  = blockIdx.x * 64;

    {
        const int kk = tid >> 2, q4 = tid & 3;
        const size_t off = ((size_t)(b * LK_ + k0 + kk)) * D_ + q4 * 16;
        const float* src = K + off;
        unsigned w[8];
#pragma unroll
        for (int i = 0; i < 4; ++i) {
            f32x4 v = *(const f32x4*)(src + 4 * i);
            w[2 * i]     = pk_bf16(v[0], v[1]);
            w[2 * i + 1] = pk_bf16(v[2], v[3]);
        }
        short* dst = Kb + off;
        *(bf16x8*)dst       = *(bf16x8*)&w[0];
        *(bf16x8*)(dst + 8) = *(bf16x8*)&w[4];
    }
    {
        const int vkg = tid & 15, vdg = tid >> 4;
        f32x4 vv[4];
#pragma unroll
        for (int p = 0; p < 4; ++p)
            vv[p] = *(const f32x4*)&V[((size_t)(b * LK_ + k0 + vkg * 4 + p)) * D_ + vdg * 4];
#pragma unroll
        for (int dr = 0; dr < 4; ++dr) {
            uint2 w = { pk_bf16(vv[0][dr], vv[1][dr]), pk_bf16(vv[2][dr], vv[3][dr]) };
            *(uint2*)&Vtb[((size_t)(b * 64 + vdg * 4 + dr)) * LK_ + k0 + vkg * 4] = w;
        }
    }
}

// ---------------------------------------------------------------------------
// Pass 1: barrier-free fragment-direct flash attention, lean registers.
// 256 threads = 4 INDEPENDENT waves; wave-task T -> (batch_rank, q-tile, split).
// ---------------------------------------------------------------------------
template<int NS>
__global__ __launch_bounds__(256, 4) void fa_frag2_kernel(
    const float* __restrict__ Q, const short* __restrict__ Kb,
    const short* __restrict__ Vtb, const int* __restrict__ vlen,
    float* __restrict__ OP, float* __restrict__ ML)
{
    const int tid  = threadIdx.x;          // 0..255
    const int wid  = tid >> 6;             // independent wave id
    const int lane = tid & 63;
    const int c31  = lane & 31;
    const int h    = lane >> 5;

    // ---- LPT wave-task remap ----
    constexpr int PB = 64 * NS;            // wave-tasks per batch
    const int T    = blockIdx.x * 4 + wid;
    const int rank = T / PB;
    const int sub  = T % PB;
    const int qw   = sub & 63;
    const int s    = sub >> 6;
    int b;
    {
        const int vj = vlen[c31];
        int r = 0;
#pragma unroll
        for (int k = 0; k < 32; ++k) {
            const int vk = __shfl(vj, k);
            r += (vk > vj) || (vk == vj && k < c31);
        }
        const unsigned long long match = __ballot(r == rank);
        b = (int)(__ffsll(match) - 1) & 31;
    }
    const int q0 = qw * 32;
    const int vl = vlen[b];
    const int nt    = (vl + 63) >> 6;
    const int chunk = (nt + NS - 1) / NS;
    const int t0    = s * chunk;
    const int t1    = min(t0 + chunk, nt);

    const float qscale = 0.125f * 1.44269504088896340736f;  // 1/sqrt(64)*log2(e)

    // ---- Q B-frags: B[k=dim][n=q], dim = ks*16 + h*8 + j ----
    unsigned qfrag[4][4];
#pragma unroll
    for (int ks = 0; ks < 4; ++ks) {
        const float* qp = Q + ((size_t)(b * LQ_ + q0 + c31)) * D_ + ks * 16 + h * 8;
        f32x4 t0v = *(const f32x4*)qp;
        f32x4 t1v = *(const f32x4*)(qp + 4);
#pragma unroll
        for (int jj = 0; jj < 2; ++jj) {
            qfrag[ks][jj]     = pk_bf16(t0v[2*jj] * qscale, t0v[2*jj+1] * qscale);
            qfrag[ks][jj + 2] = pk_bf16(t1v[2*jj] * qscale, t1v[2*jj+1] * qscale);
        }
    }

    f32x16 oacc[2];     // O^T acc: dim row = dt*32 + (r&3)+8*(r>>2)+4h, col q = c31
#pragma unroll
    for (int dt = 0; dt < 2; ++dt)
#pragma unroll
        for (int r = 0; r < 16; ++r) oacc[dt][r] = 0.f;
    float mrun = -INFINITY, lrun = 0.f;

    const short* kb  = Kb  + (size_t)b * LK_ * D_ + (size_t)c31 * D_ + h * 8;
    const short* vtb = Vtb + (size_t)b * D_ * LK_ + (size_t)c31 * LK_ + h * 8;

    for (int t = t0; t < t1; ++t) {
        const int k0 = t * 64;

        // ---- S^T = K * Q^T ; K A-frags loaded per-ss, die into MFMAs ----
        f32x16 st[2];
#pragma unroll
        for (int ss = 0; ss < 2; ++ss) {
            const short* kp = kb + (size_t)(k0 + ss * 32) * D_;
            bf16x8 kf0 = *(const bf16x8*)(kp);
            bf16x8 kf1 = *(const bf16x8*)(kp + 16);
            bf16x8 kf2 = *(const bf16x8*)(kp + 32);
            bf16x8 kf3 = *(const bf16x8*)(kp + 48);
#pragma unroll
            for (int r = 0; r < 16; ++r) st[ss][r] = 0.f;
            st[ss] = __builtin_amdgcn_mfma_f32_32x32x16_bf16(kf0, *(const bf16x8*)&qfrag[0][0], st[ss], 0, 0, 0);
            st[ss] = __builtin_amdgcn_mfma_f32_32x32x16_bf16(kf1, *(const bf16x8*)&qfrag[1][0], st[ss], 0, 0, 0);
            st[ss] = __builtin_amdgcn_mfma_f32_32x32x16_bf16(kf2, *(const bf16x8*)&qfrag[2][0], st[ss], 0, 0, 0);
            st[ss] = __builtin_amdgcn_mfma_f32_32x32x16_bf16(kf3, *(const bf16x8*)&qfrag[3][0], st[ss], 0, 0, 0);
        }

        // ---- mask tail keys >= vl ----
        if (k0 + 64 > vl) {
#pragma unroll
            for (int ss = 0; ss < 2; ++ss) {
                const int base = k0 + ss * 32 + 4 * h;
#pragma unroll
                for (int r = 0; r < 16; ++r) {
                    const int key = base + (r & 3) + 8 * (r >> 2);
                    if (key >= vl) st[ss][r] = -1e30f;
                }
            }
        }

        // ---- online softmax (log2 domain), defer-max; tree reductions ----
        float m8[8];
#pragma unroll
        for (int r = 0; r < 8; ++r)
            m8[r] = fmaxf(fmaxf(st[0][r], st[0][r + 8]),
                          fmaxf(st[1][r], st[1][r + 8]));
#pragma unroll
        for (int o = 4; o; o >>= 1)
#pragma unroll
            for (int r = 0; r < o; ++r) m8[r] = fmaxf(m8[r], m8[r + o]);
        const float tm = xhalf_max(m8[0]);

        if (__any(tm > mrun + 8.f)) {          // rare after the first tile
            const float mnew = fmaxf(mrun, tm);
            const float corr = exp2f(mrun - mnew);
            lrun *= corr;
#pragma unroll
            for (int dt = 0; dt < 2; ++dt)
#pragma unroll
                for (int r = 0; r < 16; ++r) oacc[dt][r] *= corr;
            mrun = mnew;
        }
#pragma unroll
        for (int ss = 0; ss < 2; ++ss)
#pragma unroll
            for (int r = 0; r < 16; ++r)
                st[ss][r] = exp2f(st[ss][r] - mrun);   // bounded by 2^8
        float s8[8];
#pragma unroll
        for (int r = 0; r < 8; ++r)
            s8[r] = (st[0][r] + st[0][r + 8]) + (st[1][r] + st[1][r + 8]);
#pragma unroll
        for (int o = 4; o; o >>= 1)
#pragma unroll
            for (int r = 0; r < o; ++r) s8[r] += s8[r + o];
        lrun += xhalf_add(s8[0]);

        // ---- pack P and build ALL P A-frags first (pk dies here) ----
        unsigned pfall[4][4];
#pragma unroll
        for (int kq = 0; kq < 4; ++kq) {
            const int ss = kq >> 1;
            const int A4 = (kq & 1) * 4;
            unsigned p0 = pk_bf16(st[ss][2*(A4+0)], st[ss][2*(A4+0)+1]);
            unsigned p1 = pk_bf16(st[ss][2*(A4+1)], st[ss][2*(A4+1)+1]);
            unsigned p2 = pk_bf16(st[ss][2*(A4+2)], st[ss][2*(A4+2)+1]);
            unsigned p3 = pk_bf16(st[ss][2*(A4+3)], st[ss][2*(A4+3)+1]);
            u32x2 r02 = plswap(p0, p2);
            u32x2 r13 = plswap(p1, p3);
            pfall[kq][0] = r02[0]; pfall[kq][1] = r13[0];
            pfall[kq][2] = r02[1]; pfall[kq][3] = r13[1];
        }

        // ---- O^T += V^T * P^T ; V A-frags loaded per-dt, die into MFMAs ----
#pragma unroll
        for (int dt = 0; dt < 2; ++dt) {
            const short* vp = vtb + (size_t)(dt * 32) * LK_ + k0;
            bf16x8 vf0 = *(const bf16x8*)(vp);
            bf16x8 vf1 = *(const bf16x8*)(vp + 16);
            bf16x8 vf2 = *(const bf16x8*)(vp + 32);
            bf16x8 vf3 = *(const bf16x8*)(vp + 48);
            oacc[dt] = __builtin_amdgcn_mfma_f32_32x32x16_bf16(vf0, *(const bf16x8*)&pfall[0][0], oacc[dt], 0, 0, 0);
            oacc[dt] = __builtin_amdgcn_mfma_f32_32x32x16_bf16(vf1, *(const bf16x8*)&pfall[1][0], oacc[dt], 0, 0, 0);
            oacc[dt] = __builtin_amdgcn_mfma_f32_32x32x16_bf16(vf2, *(const bf16x8*)&pfall[2][0], oacc[dt], 0, 0, 0);
            oacc[dt] = __builtin_amdgcn_mfma_f32_32x32x16_bf16(vf3, *(const bf16x8*)&pfall[3][0], oacc[dt], 0, 0, 0);
        }
    }

    // ---- epilogue: store UNNORMALIZED partial O^T and (m, l) ----
    const size_t row = (size_t)s * (B_ * LQ_) + b * LQ_ + q0 + c31;
    float* op = OP + row * D_;
#pragma unroll
    for (int dt = 0; dt < 2; ++dt)
#pragma unroll
        for (int g = 0; g < 4; ++g) {
            f32x4 v;
#pragma unroll
            for (int j = 0; j < 4; ++j) v[j] = oacc[dt][4 * g + j];
            *(f32x4*)(op + dt * 32 + 8 * g + 4 * h) = v;
        }
    if (h == 0)
        *(float2*)&ML[row * 2] = float2{mrun, lrun};   // (-inf, 0) if empty split
}

// ---------------------------------------------------------------------------
// Pass 2: merge NS partials per q row. One thread per (row, 4-dim chunk).
// ---------------------------------------------------------------------------
template<int NS>
__global__ __launch_bounds__(256) void fa_merge_kernel(
    const float* __restrict__ OP, const float* __restrict__ ML,
    float* __restrict__ O)
{
    const int g   = blockIdx.x * 256 + threadIdx.x;   // 0 .. B*LQ*16-1
    const int row = g >> 4;                            // b*LQ + q
    const int qd  = (g & 15) * 4;

    float mf = -INFINITY;
#pragma unroll
    for (int s = 0; s < NS; ++s) {
        float2 ml = *(const float2*)&ML[((size_t)s * (B_ * LQ_) + row) * 2];
        mf = fmaxf(mf, ml.x);                          // split 0 always finite
    }
    float den = 0.f;
    f32x4 acc = {0.f, 0.f, 0.f, 0.f};
#pragma unroll
    for (int s = 0; s < NS; ++s) {
        const size_t srow = (size_t)s * (B_ * LQ_) + row;
        float2 ml = *(const float2*)&ML[srow * 2];
        const float c = exp2f(ml.x - mf);              // 0 for empty splits
        den += c * ml.y;
        f32x4 v = *(const f32x4*)&OP[srow * D_ + qd];
        acc += v * c;                                  // empty split: c=0, v=0
    }
    const float inv = 1.f / den;
    *(f32x4*)(O + (size_t)row * D_ + qd) = acc * inv;
}

// ---------------------------------------------------------------------------
// Fallback A: r15 LDS-staged split kernel (proven, 66us).
// ---------------------------------------------------------------------------
template<int NS>
__global__ __launch_bounds__(256, 2) void fa_split9_kernel(
    const float* __restrict__ Q, const float* __restrict__ K,
    const float* __restrict__ V, const int* __restrict__ vlen,
    float* __restrict__ OP, float* __restrict__ ML)
{
    __shared__ __align__(16) short Kl[2][64 * 64];
    __shared__ __align__(16) short Vt[2][64 * 64];

    const int tid  = threadIdx.x;
    const int wid  = tid >> 6;
    const int lane = tid & 63;
    const int c31  = lane & 31;
    const int h    = lane >> 5;

    constexpr int PB = 16 * NS;
    const int L    = blockIdx.x;
    const int rank = L / PB;
    const int sub  = L % PB;
    const int qb   = sub & 15;
    const int s    = sub >> 4;
    int b;
    {
        const int vj = vlen[c31];
        int r = 0;
#pragma unroll
        for (int k = 0; k < 32; ++k) {
            const int vk = __shfl(vj, k);
            r += (vk > vj) || (vk == vj && k < c31);
        }
        const unsigned long long match = __ballot(r == rank);
        b = (int)(__ffsll(match) - 1) & 31;
    }
    const int q0 = qb * 128 + wid * 32;
    const int vl = vlen[b];
    const int nt    = (vl + 63) >> 6;
    const int chunk = (nt + NS - 1) / NS;
    const int t0    = s * chunk;
    const int t1    = min(t0 + chunk, nt);

    const float qscale = 0.125f * 1.44269504088896340736f;

    unsigned qfrag[4][4];
#pragma unroll
    for (int ks = 0; ks < 4; ++ks) {
        const float* qp = Q + ((size_t)(b * LQ_ + q0 + c31)) * D_ + ks * 16 + h * 8;
        f32x4 t0v = *(const f32x4*)qp;
        f32x4 t1v = *(const f32x4*)(qp + 4);
#pragma unroll
        for (int jj = 0; jj < 2; ++jj) {
            qfrag[ks][jj]     = pk_bf16(t0v[2*jj] * qscale, t0v[2*jj+1] * qscale);
            qfrag[ks][jj + 2] = pk_bf16(t1v[2*jj] * qscale, t1v[2*jj+1] * qscale);
        }
    }

    f32x16 oacc[2];
#pragma unroll
    for (int dt = 0; dt < 2; ++dt)
#pragma unroll
        for (int r = 0; r < 16; ++r) oacc[dt][r] = 0.f;
    float mrun = -INFINITY, lrun = 0.f;

    const int skey = tid >> 2, skh = tid & 3;
    const int vkg = tid >> 4, vdg = tid & 15;

    const float* kgp = K + ((size_t)(b * LK_ + skey)) * D_ + skh * 16;
    const float* vgp = V + ((size_t)(b * LK_ + vkg * 4)) * D_ + vdg * 4;

    f32x4 kr[4], vr[4];
    if (t0 < t1) {
        const size_t off = (size_t)t0 * 64 * D_;
#pragma unroll
        for (int i = 0; i < 4; ++i) kr[i] = *(const f32x4*)(kgp + off + 4 * i);
#pragma unroll
        for (int i = 0; i < 4; ++i) vr[i] = *(const f32x4*)(vgp + off + (size_t)i * D_);
    }

    for (int t = t0; t < t1; ++t) {
        const int k0 = t * 64;
        const int buf = t & 1;
        {
            unsigned pk32[8];
#pragma unroll
            for (int m = 0; m < 8; ++m)
                pk32[m] = pk_bf16(kr[m >> 1][2 * (m & 1)], kr[m >> 1][2 * (m & 1) + 1]);
#pragma unroll
            for (int cch = 0; cch < 2; ++cch) {
                const int pos = (skh * 2 + cch) ^ (skey & 7);
                *(bf16x8*)&Kl[buf][skey * 64 + pos * 8] = *(bf16x8*)&pk32[4 * cch];
            }
#pragma unroll
            for (int dr = 0; dr < 4; ++dr) {
                const unsigned w0 = pk_bf16(vr[0][dr], vr[1][dr]);
                const unsigned w1 = pk_bf16(vr[2][dr], vr[3][dr]);
                const int dim = vdg * 4 + dr;
                const int pos = (vkg >> 1) ^ (dim & 7);
                *(uint2*)&Vt[buf][dim * 64 + pos * 8 + (vkg & 1) * 4] = uint2{w0, w1};
            }
        }
        __syncthreads();
        if (t + 1 < t1) {
            const float* kn = kgp + (size_t)(k0 + 64) * D_;
            const float* vn = vgp + (size_t)(k0 + 64) * D_;
#pragma unroll
            for (int i = 0; i < 4; ++i) kr[i] = *(const f32x4*)(kn + 4 * i);
#pragma unroll
            for (int i = 0; i < 4; ++i) vr[i] = *(const f32x4*)(vn + (size_t)i * D_);
        }

        f32x16 st[2];
#pragma unroll
        for (int ss = 0; ss < 2; ++ss) {
#pragma unroll
            for (int r = 0; r < 16; ++r) st[ss][r] = 0.f;
#pragma unroll
            for (int ks = 0; ks < 4; ++ks) {
                const int pos = (ks * 2 + h) ^ (c31 & 7);
                bf16x8 kf = *(const bf16x8*)&Kl[buf][(ss * 32 + c31) * 64 + pos * 8];
                st[ss] = __builtin_amdgcn_mfma_f32_32x32x16_bf16(
                    kf, *(const bf16x8*)&qfrag[ks][0], st[ss], 0, 0, 0);
            }
        }
        if (k0 + 64 > vl) {
#pragma unroll
            for (int ss = 0; ss < 2; ++ss) {
                const int base = k0 + ss * 32 + 4 * h;
#pragma unroll
                for (int r = 0; r < 16; ++r) {
                    const int key = base + (r & 3) + 8 * (r >> 2);
                    if (key >= vl) st[ss][r] = -1e30f;
                }
            }
        }
        float m8[8];
#pragma unroll
        for (int r = 0; r < 8; ++r)
            m8[r] = fmaxf(fmaxf(st[0][r], st[0][r + 8]),
                          fmaxf(st[1][r], st[1][r + 8]));
#pragma unroll
        for (int o = 4; o; o >>= 1)
#pragma unroll
            for (int r = 0; r < o; ++r) m8[r] = fmaxf(m8[r], m8[r + o]);
        const float tm = xhalf_max(m8[0]);
        if (__any(tm > mrun + 8.f)) {
            const float mnew = fmaxf(mrun, tm);
            const float corr = exp2f(mrun - mnew);
            lrun *= corr;
#pragma unroll
            for (int dt = 0; dt < 2; ++dt)
#pragma unroll
                for (int r = 0; r < 16; ++r) oacc[dt][r] *= corr;
            mrun = mnew;
        }
#pragma unroll
        for (int ss = 0; ss < 2; ++ss)
#pragma unroll
            for (int r = 0; r < 16; ++r)
                st[ss][r] = exp2f(st[ss][r] - mrun);
        float s8[8];
#pragma unroll
        for (int r = 0; r < 8; ++r)
            s8[r] = (st[0][r] + st[0][r + 8]) + (st[1][r] + st[1][r + 8]);
#pragma unroll
        for (int o = 4; o; o >>= 1)
#pragma unroll
            for (int r = 0; r < o; ++r) s8[r] += s8[r + o];
        lrun += xhalf_add(s8[0]);

        unsigned pk[2][8];
#pragma unroll
        for (int ss = 0; ss < 2; ++ss)
#pragma unroll
            for (int m = 0; m < 8; ++m)
                pk[ss][m] = pk_bf16(st[ss][2 * m], st[ss][2 * m + 1]);
#pragma unroll
        for (int kq = 0; kq < 4; ++kq) {
            const int ss = kq >> 1, A4 = (kq & 1) * 4;
            u32x2 r02 = plswap(pk[ss][A4],     pk[ss][A4 + 2]);
            u32x2 r13 = plswap(pk[ss][A4 + 1], pk[ss][A4 + 3]);
            unsigned pf[4] = {r02[0], r13[0], r02[1], r13[1]};
            const bf16x8 pfr = *(const bf16x8*)&pf[0];
#pragma unroll
            for (int dt = 0; dt < 2; ++dt) {
                const int pos = (kq * 2 + h) ^ (c31 & 7);
                bf16x8 vfv = *(const bf16x8*)&Vt[buf][(dt * 32 + c31) * 64 + pos * 8];
                oacc[dt] = __builtin_amdgcn_mfma_f32_32x32x16_bf16(vfv, pfr, oacc[dt], 0, 0, 0);
            }
        }
    }

    const size_t row = (size_t)s * (B_ * LQ_) + b * LQ_ + q0 + c31;
    float* op = OP + row * D_;
#pragma unroll
    for (int dt = 0; dt < 2; ++dt)
#pragma unroll
        for (int g = 0; g < 4; ++g) {
            f32x4 v;
#pragma unroll
            for (int j = 0; j < 4; ++j) v[j] = oacc[dt][4 * g + j];
            *(f32x4*)(op + dt * 32 + 8 * g + 4 * h) = v;
        }
    if (h == 0)
        *(float2*)&ML[row * 2] = float2{mrun, lrun};
}

// ---------------------------------------------------------------------------
// Fallback B: monolithic kernel, no workspace.
// ---------------------------------------------------------------------------
__global__ __launch_bounds__(128, 2) void fa_mono_kernel(
    const float* __restrict__ Q, const float* __restrict__ K,
    const float* __restrict__ V, const int* __restrict__ vlen,
    float* __restrict__ O)
{
    __shared__ __align__(16) short Kl[2][64 * 64];
    __shared__ __align__(16) short Vt[2][64 * 64];

    const int tid  = threadIdx.x;
    const int wave = tid >> 6;
    const int lane = tid & 63;
    const int c31  = lane & 31;
    const int h    = lane >> 5;

    const int b  = blockIdx.y;
    const int q0 = blockIdx.x * 64 + wave * 32;
    const int vl = vlen[b];
    const int nt = (vl + 63) >> 6;

    const float qscale = 0.125f * 1.44269504088896340736f;

    unsigned qfrag[4][4];
#pragma unroll
    for (int ks = 0; ks < 4; ++ks) {
        const float* qp = Q + ((size_t)(b * LQ_ + q0 + c31)) * D_ + ks * 16 + h * 8;
        f32x4 t0 = *(const f32x4*)qp;
        f32x4 t1 = *(const f32x4*)(qp + 4);
#pragma unroll
        for (int jj = 0; jj < 2; ++jj) {
            qfrag[ks][jj]     = pk_bf16(t0[2*jj] * qscale, t0[2*jj+1] * qscale);
            qfrag[ks][jj + 2] = pk_bf16(t1[2*jj] * qscale, t1[2*jj+1] * qscale);
        }
    }

    f32x16 oacc[2];
#pragma unroll
    for (int dt = 0; dt < 2; ++dt)
#pragma unroll
        for (int r = 0; r < 16; ++r) oacc[dt][r] = 0.f;
    float mrun = -INFINITY, lrun = 0.f;

    const int skey = tid >> 1, skh = tid & 1;
    const int vkg = tid >> 4, vdg = tid & 15;

    const float* kgp = K + ((size_t)(b * LK_ + skey)) * D_ + skh * 32;
    const float* vgp = V + ((size_t)(b * LK_ + vkg * 8)) * D_ + vdg * 4;

    f32x4 kr[8], vr[8];
#pragma unroll
    for (int i = 0; i < 8; ++i) kr[i] = *(const f32x4*)(kgp + 4 * i);
#pragma unroll
    for (int i = 0; i < 8; ++i) vr[i] = *(const f32x4*)(vgp + (size_t)i * D_);

    for (int t = 0; t < nt; ++t) {
        const int k0 = t * 64;
        const int buf = t & 1;
        {
            unsigned pk32[16];
#pragma unroll
            for (int m = 0; m < 16; ++m)
                pk32[m] = pk_bf16(kr[m >> 1][2 * (m & 1)], kr[m >> 1][2 * (m & 1) + 1]);
#pragma unroll
            for (int cch = 0; cch < 4; ++cch) {
                const int pos = (skh * 4 + cch) ^ (skey & 7);
                *(bf16x8*)&Kl[buf][skey * 64 + pos * 8] = *(bf16x8*)&pk32[4 * cch];
            }
#pragma unroll
            for (int dr = 0; dr < 4; ++dr) {
                unsigned w[4];
#pragma unroll
                for (int p = 0; p < 4; ++p)
                    w[p] = pk_bf16(vr[2 * p][dr], vr[2 * p + 1][dr]);
                const int dim = vdg * 4 + dr;
                const int pos = vkg ^ (dim & 7);
                *(bf16x8*)&Vt[buf][dim * 64 + pos * 8] = *(bf16x8*)&w[0];
            }
        }
        if (t + 1 < nt) {
            const float* kn = kgp + (size_t)(k0 + 64) * D_;
            const float* vn = vgp + (size_t)(k0 + 64) * D_;
#pragma unroll
            for (int i = 0; i < 8; ++i) kr[i] = *(const f32x4*)(kn + 4 * i);
#pragma unroll
            for (int i = 0; i < 8; ++i) vr[i] = *(const f32x4*)(vn + (size_t)i * D_);
        }
        __syncthreads();

        f32x16 st[2];
#pragma unroll
        for (int ss = 0; ss < 2; ++ss) {
#pragma unroll
            for (int r = 0; r < 16; ++r) st[ss][r] = 0.f;
#pragma unroll
            for (int ks = 0; ks < 4; ++ks) {
                const int pos = (ks * 2 + h) ^ (c31 & 7);
                bf16x8 kf = *(const bf16x8*)&Kl[buf][(ss * 32 + c31) * 64 + pos * 8];
                st[ss] = __builtin_amdgcn_mfma_f32_32x32x16_bf16(
                    kf, *(const bf16x8*)&qfrag[ks][0], st[ss], 0, 0, 0);
            }
        }
        if (k0 + 64 > vl) {
#pragma unroll
            for (int ss = 0; ss < 2; ++ss) {
                const int base = k0 + ss * 32 + 4 * h;
#pragma unroll
                for (int r = 0; r < 16; ++r) {
                    const int key = base + (r & 3) + 8 * (r >> 2);
                    if (key >= vl) st[ss][r] = -1e30f;
                }
            }
        }
        float tm = st[0][0];
#pragma unroll
        for (int ss = 0; ss < 2; ++ss)
#pragma unroll
            for (int r = 0; r < 16; ++r) tm = fmaxf(tm, st[ss][r]);
        tm = fmaxf(tm, __shfl_xor(tm, 32));
        if (__any(tm > mrun + 8.f)) {
            const float mnew = fmaxf(mrun, tm);
            const float corr = exp2f(mrun - mnew);
            lrun *= corr;
#pragma unroll
            for (int dt = 0; dt < 2; ++dt)
#pragma unroll
                for (int r = 0; r < 16; ++r) oacc[dt][r] *= corr;
            mrun = mnew;
        }
        float rs = 0.f;
#pragma unroll
        for (int ss = 0; ss < 2; ++ss)
#pragma unroll
            for (int r = 0; r < 16; ++r) {
                const float p = exp2f(st[ss][r] - mrun);
                st[ss][r] = p;
                rs += p;
            }
        rs += __shfl_xor(rs, 32);
        lrun += rs;

        unsigned pk[2][8];
#pragma unroll
        for (int ss = 0; ss < 2; ++ss)
#pragma unroll
            for (int m = 0; m < 8; ++m)
                pk[ss][m] = pk_bf16(st[ss][2 * m], st[ss][2 * m + 1]);
#pragma unroll
        for (int kq = 0; kq < 4; ++kq) {
            const int ss = kq >> 1, A4 = (kq & 1) * 4;
            unsigned p0 = pk[ss][A4], p1 = pk[ss][A4+1], p2 = pk[ss][A4+2], p3 = pk[ss][A4+3];
            unsigned xp0 = __shfl_xor((int)p0, 32);
            unsigned xp1 = __shfl_xor((int)p1, 32);
            unsigned xp2 = __shfl_xor((int)p2, 32);
            unsigned xp3 = __shfl_xor((int)p3, 32);
            unsigned pf[4];
            pf[0] = h ? xp2 : p0;
            pf[1] = h ? xp3 : p1;
            pf[2] = h ? p2  : xp0;
            pf[3] = h ? p3  : xp1;
            const bf16x8 pfr = *(const bf16x8*)&pf[0];
#pragma unroll
            for (int dt = 0; dt < 2; ++dt) {
                const int pos = (kq * 2 + h) ^ (c31 & 7);
                bf16x8 vf = *(const bf16x8*)&Vt[buf][(dt * 32 + c31) * 64 + pos * 8];
                oacc[dt] = __builtin_amdgcn_mfma_f32_32x32x16_bf16(vf, pfr, oacc[dt], 0, 0, 0);
            }
        }
    }

    const float inv = 1.f / lrun;
    float* op = O + ((size_t)(b * LQ_ + q0 + c31)) * D_;
#pragma unroll
    for (int dt = 0; dt < 2; ++dt)
#pragma unroll
        for (int g = 0; g < 4; ++g) {
            f32x4 v;
#pragma unroll
            for (int j = 0; j < 4; ++j) v[j] = oacc[dt][4 * g + j] * inv;
            *(f32x4*)(op + dt * 32 + 8 * g + 4 * h) = v;
        }
}

extern "C" void kernel_launch(void* const* d_in, const int* in_sizes, int n_in,
                              void* d_out, int out_size, void* d_ws, size_t ws_size,
                              hipStream_t stream) {
    const float* Q    = (const float*)d_in[0];
    const float* K    = (const float*)d_in[1];
    const float* V    = (const float*)d_in[2];
    const int*   vlen = (const int*)d_in[3];
    float*       O    = (float*)d_out;

    const size_t rows    = (size_t)B_ * LQ_;
    const size_t kvElems = (size_t)B_ * LK_ * D_;          // per tensor
    auto needP = [&](int ns) { return (size_t)ns * rows * (D_ + 2) * sizeof(float); };
    const size_t needKV = 2 * kvElems * sizeof(short);     // Kb + Vtb (33.6 MB)

    constexpr int NS = 4;

    if (d_ws && ws_size >= needP(NS) + needKV) {
        // ---- fragment-direct path ----
        float* OP  = (float*)d_ws;
        float* ML  = OP + (size_t)NS * rows * D_;
        short* Kb  = (short*)(ML + (size_t)NS * rows * 2);
        short* Vtb = Kb + kvElems;

        fa_cvt_kernel<<<dim3(LK_ / 64, B_), dim3(256), 0, stream>>>(K, V, Kb, Vtb);

        const unsigned nblk = (unsigned)(64 * B_ * NS / 4);   // 2048 blocks, 4 wave-tasks each
        fa_frag2_kernel<NS><<<dim3(nblk), dim3(256), 0, stream>>>(Q, Kb, Vtb, vlen, OP, ML);

        dim3 g2((unsigned)((rows * (D_ / 4)) / 256));
        fa_merge_kernel<NS><<<g2, dim3(256), 0, stream>>>(OP, ML, O);
        return;
    }

    if (d_ws && ws_size >= needP(NS)) {
        // ---- r15 LDS-staged path (proven) ----
        float* OP = (float*)d_ws;
        float* ML = OP + (size_t)NS * rows * D_;
        const unsigned nblk = (unsigned)(16 * B_ * NS);
        fa_split9_kernel<NS><<<dim3(nblk), dim3(256), 0, stream>>>(Q, K, V, vlen, OP, ML);
        dim3 g2((unsigned)((rows * (D_ / 4)) / 256));
        fa_merge_kernel<NS><<<g2, dim3(256), 0, stream>>>(OP, ML, O);
        return;
    }

    dim3 grid(LQ_ / 64, B_);
    fa_mono_kernel<<<grid, dim3(128), 0, stream>>>(Q, K, V, vlen, O);
}

// Round 15
// 161.374 us; speedup vs baseline: 1.3016x; 1.1945x over previous
//
#include <hip/hip_runtime.h>
#include <hip/hip_bf16.h>
#include <math.h>

// Masked dot-product attention, bf16 MFMA flash kernel, round 18.
// B=32, LQ=LK=2048, D=64. S^T = K*Q^T and O^T = V^T*P^T with 32x32x16 MFMA.
// = r14/r15 proven base (split9 66us) + ONE change: split launch bound
//   (256,2) -> (256,6).
//  - r17 post-mortem: fragment-direct (no LDS) is structurally worse (98us,
//    MfmaUtil 7%) - K/V L2-latency chains per tile, no reuse. Reverted per
//    pre-commitment.
//  - Mechanism: natural allocation is 84 VGPR; (256,6) caps at ~85 which
//    FITS (unlike r7: cap 64 vs ~80 live -> spill), and contractually raises
//    the wave cap to 6 waves/SIMD = 24/CU (vs 16 if HW rounds 84 into the
//    65-128 granule at 4/SIMD).
//  - Falsifiable: VGPR<=85 & WRITE~67.6MB (no spill); occupancy 25->30-38.

#define B_    32
#define LQ_   2048
#define LK_   2048
#define D_    64

typedef __attribute__((ext_vector_type(8)))  short bf16x8;
typedef __attribute__((ext_vector_type(4)))  float f32x4;
typedef __attribute__((ext_vector_type(16))) float f32x16;
typedef __attribute__((ext_vector_type(2)))  unsigned u32x2;

static __device__ __forceinline__ unsigned pk_bf16(float a, float b) {
    __hip_bfloat162 h = __float22bfloat162_rn(float2{a, b});
    return *(unsigned*)&h;   // x in low 16 bits, y in high
}

// v_permlane32_swap_b32 via builtin (hazard-safe). Semantics: swaps the high
// 32 lanes of the first operand with the low 32 lanes of the second.
// r[0] = {a.lanes[0:31], b.lanes[0:31]}, r[1] = {a.lanes[32:63], b.lanes[32:63]}.
static __device__ __forceinline__ u32x2 plswap(unsigned a, unsigned b) {
    return __builtin_amdgcn_permlane32_swap(a, b, false, false);
}
// cross-half (lane ^ 32) reduce helpers (orientation-invariant: a == b)
static __device__ __forceinline__ float xhalf_max(float x) {
    u32x2 r = plswap(__float_as_uint(x), __float_as_uint(x));
    return fmaxf(__uint_as_float(r[0]), __uint_as_float(r[1]));
}
static __device__ __forceinline__ float xhalf_add(float x) {
    u32x2 r = plswap(__float_as_uint(x), __float_as_uint(x));
    return __uint_as_float(r[0]) + __uint_as_float(r[1]);
}

// ---------------------------------------------------------------------------
// Pass 1: per-(qblock=128 rows, batch, split) flash attention over [t0, t1).
// 256 threads = 4 q-waves sharing one double-buffered 64x64 K/V LDS tile.
// LPT: blockIdx.x -> (batch_rank, qblock, split); batch = rank-th longest vl,
// computed per-wave with shfl+ballot (no LDS, no barrier).
// Writes UNNORMALIZED O^T partial + (m, l) per q row.
// ---------------------------------------------------------------------------
template<int NS>
__global__ __launch_bounds__(256, 6) void fa_split10_kernel(
    const float* __restrict__ Q, const float* __restrict__ K,
    const float* __restrict__ V, const int* __restrict__ vlen,
    float* __restrict__ OP, float* __restrict__ ML)
{
    __shared__ __align__(16) short Kl[2][64 * 64];
    __shared__ __align__(16) short Vt[2][64 * 64];

    const int tid  = threadIdx.x;          // 0..255
    const int wid  = tid >> 6;             // 0..3  (q sub-block)
    const int lane = tid & 63;
    const int c31  = lane & 31;
    const int h    = lane >> 5;

    // ---- LPT remap (LDS-free): rank batches by vl DESC, index tie-break ----
    constexpr int PB = 16 * NS;            // blocks per batch (16,32,64)
    const int L    = blockIdx.x;
    const int rank = L / PB;               // compile-time divisor
    const int sub  = L % PB;
    const int qb   = sub & 15;
    const int s    = sub >> 4;
    int b;
    {
        const int vj = vlen[c31];          // lanes j and j+32 hold vlen[j]
        int r = 0;
#pragma unroll
        for (int k = 0; k < 32; ++k) {
            const int vk = __shfl(vj, k);  // broadcast vlen[k]
            r += (vk > vj) || (vk == vj && k < c31);
        }
        const unsigned long long match = __ballot(r == rank);
        b = (int)(__ffsll(match) - 1) & 31;
    }
    const int q0 = qb * 128 + wid * 32;
    const int vl = vlen[b];
    const int nt    = (vl + 63) >> 6;
    const int chunk = (nt + NS - 1) / NS;
    const int t0    = s * chunk;
    const int t1    = min(t0 + chunk, nt);

    const float qscale = 0.125f * 1.44269504088896340736f;  // 1/sqrt(64)*log2(e)

    // ---- Q B-frags in registers: B[k=dim][n=q], dim = ks*16 + h*8 + j ----
    unsigned qfrag[4][4];
#pragma unroll
    for (int ks = 0; ks < 4; ++ks) {
        const float* qp = Q + ((size_t)(b * LQ_ + q0 + c31)) * D_ + ks * 16 + h * 8;
        f32x4 t0v = *(const f32x4*)qp;
        f32x4 t1v = *(const f32x4*)(qp + 4);
#pragma unroll
        for (int jj = 0; jj < 2; ++jj) {
            qfrag[ks][jj]     = pk_bf16(t0v[2*jj] * qscale, t0v[2*jj+1] * qscale);
            qfrag[ks][jj + 2] = pk_bf16(t1v[2*jj] * qscale, t1v[2*jj+1] * qscale);
        }
    }

    f32x16 oacc[2];     // O^T acc: dim row = dt*32 + (r&3)+8*(r>>2)+4h, col q = c31
#pragma unroll
    for (int dt = 0; dt < 2; ++dt)
#pragma unroll
        for (int r = 0; r < 16; ++r) oacc[dt][r] = 0.f;
    float mrun = -INFINITY, lrun = 0.f;

    // ---- staging maps (256 threads stage the whole 64x64 K and V tiles) ----
    const int skey = tid >> 2, skh = tid & 3;          // K: quarter-row each
    const int vkg = tid >> 4, vdg = tid & 15;          // V: 4 keys x 4 dims

    const float* kgp = K + ((size_t)(b * LK_ + skey)) * D_ + skh * 16;
    const float* vgp = V + ((size_t)(b * LK_ + vkg * 4)) * D_ + vdg * 4;

    f32x4 kr[4], vr[4];
    // ---- prologue: prefetch tile t0 into registers ----
    if (t0 < t1) {
        const size_t off = (size_t)t0 * 64 * D_;
#pragma unroll
        for (int i = 0; i < 4; ++i) kr[i] = *(const f32x4*)(kgp + off + 4 * i);
#pragma unroll
        for (int i = 0; i < 4; ++i) vr[i] = *(const f32x4*)(vgp + off + (size_t)i * D_);
    }

    for (int t = t0; t < t1; ++t) {
        const int k0 = t * 64;
        const int buf = t & 1;

        // ---- cvt + write tile t to LDS ----
        {
            unsigned pk32[8];
#pragma unroll
            for (int m = 0; m < 8; ++m)
                pk32[m] = pk_bf16(kr[m >> 1][2 * (m & 1)], kr[m >> 1][2 * (m & 1) + 1]);
#pragma unroll
            for (int cch = 0; cch < 2; ++cch) {
                const int pos = (skh * 2 + cch) ^ (skey & 7);
                *(bf16x8*)&Kl[buf][skey * 64 + pos * 8] = *(bf16x8*)&pk32[4 * cch];
            }
#pragma unroll
            for (int dr = 0; dr < 4; ++dr) {
                const unsigned w0 = pk_bf16(vr[0][dr], vr[1][dr]);
                const unsigned w1 = pk_bf16(vr[2][dr], vr[3][dr]);
                const int dim = vdg * 4 + dr;
                const int pos = (vkg >> 1) ^ (dim & 7);
                uint2* dst = (uint2*)&Vt[buf][dim * 64 + pos * 8 + (vkg & 1) * 4];
                *dst = uint2{w0, w1};
            }
        }
        __syncthreads();

        // ---- issue prefetch for tile t+1 (flies under the compute phase) ----
        if (t + 1 < t1) {
            const float* kn = kgp + (size_t)(k0 + 64) * D_;
            const float* vn = vgp + (size_t)(k0 + 64) * D_;
#pragma unroll
            for (int i = 0; i < 4; ++i) kr[i] = *(const f32x4*)(kn + 4 * i);
#pragma unroll
            for (int i = 0; i < 4; ++i) vr[i] = *(const f32x4*)(vn + (size_t)i * D_);
        }

        // ---- S^T = K * Q^T : 2 key-tiles x 4 k-steps of 32x32x16 ----
        f32x16 st[2];
#pragma unroll
        for (int ss = 0; ss < 2; ++ss) {
#pragma unroll
            for (int r = 0; r < 16; ++r) st[ss][r] = 0.f;
#pragma unroll
            for (int ks = 0; ks < 4; ++ks) {
                const int pos = (ks * 2 + h) ^ (c31 & 7);
                bf16x8 kf = *(const bf16x8*)&Kl[buf][(ss * 32 + c31) * 64 + pos * 8];
                st[ss] = __builtin_amdgcn_mfma_f32_32x32x16_bf16(
                    kf, *(const bf16x8*)&qfrag[ks][0], st[ss], 0, 0, 0);
            }
        }

        // ---- mask tail keys >= vl ----
        if (k0 + 64 > vl) {
#pragma unroll
            for (int ss = 0; ss < 2; ++ss) {
                const int base = k0 + ss * 32 + 4 * h;
#pragma unroll
                for (int r = 0; r < 16; ++r) {
                    const int key = base + (r & 3) + 8 * (r >> 2);
                    if (key >= vl) st[ss][r] = -1e30f;
                }
            }
        }

        // ---- online softmax (log2 domain), defer-max; tree reductions ----
        float m8[8];
#pragma unroll
        for (int r = 0; r < 8; ++r)
            m8[r] = fmaxf(fmaxf(st[0][r], st[0][r + 8]),
                          fmaxf(st[1][r], st[1][r + 8]));
#pragma unroll
        for (int o = 4; o; o >>= 1)
#pragma unroll
            for (int r = 0; r < o; ++r) m8[r] = fmaxf(m8[r], m8[r + o]);
        const float tm = xhalf_max(m8[0]);

        if (__any(tm > mrun + 8.f)) {          // rare after the first tile
            const float mnew = fmaxf(mrun, tm);
            const float corr = exp2f(mrun - mnew);
            lrun *= corr;
#pragma unroll
            for (int dt = 0; dt < 2; ++dt)
#pragma unroll
                for (int r = 0; r < 16; ++r) oacc[dt][r] *= corr;
            mrun = mnew;
        }
#pragma unroll
        for (int ss = 0; ss < 2; ++ss)
#pragma unroll
            for (int r = 0; r < 16; ++r)
                st[ss][r] = exp2f(st[ss][r] - mrun);   // bounded by 2^8
        float s8[8];
#pragma unroll
        for (int r = 0; r < 8; ++r)
            s8[r] = (st[0][r] + st[0][r + 8]) + (st[1][r] + st[1][r + 8]);
#pragma unroll
        for (int o = 4; o; o >>= 1)
#pragma unroll
            for (int r = 0; r < o; ++r) s8[r] += s8[r + o];
        lrun += xhalf_add(s8[0]);

        // ---- pack P to bf16 pairs ----
        unsigned pk[2][8];
#pragma unroll
        for (int ss = 0; ss < 2; ++ss)
#pragma unroll
            for (int m = 0; m < 8; ++m)
                pk[ss][m] = pk_bf16(st[ss][2 * m], st[ss][2 * m + 1]);

        // ---- O^T += V^T * P^T : 4 k-steps x 2 dim-tiles ----
        //  P fragment exchange: r = plswap(p0, p2) -> r[0] = {p0.low, p2.low}
        //  = pf0, r[1] = {p0.high, p2.high} = pf2.
#pragma unroll
        for (int kq = 0; kq < 4; ++kq) {
            const int ss = kq >> 1, A4 = (kq & 1) * 4;
            u32x2 r02 = plswap(pk[ss][A4],     pk[ss][A4 + 2]);
            u32x2 r13 = plswap(pk[ss][A4 + 1], pk[ss][A4 + 3]);
            unsigned pf[4] = {r02[0], r13[0], r02[1], r13[1]};
            const bf16x8 pfr = *(const bf16x8*)&pf[0];
#pragma unroll
            for (int dt = 0; dt < 2; ++dt) {
                const int pos = (kq * 2 + h) ^ (c31 & 7);
                bf16x8 vf = *(const bf16x8*)&Vt[buf][(dt * 32 + c31) * 64 + pos * 8];
                oacc[dt] = __builtin_amdgcn_mfma_f32_32x32x16_bf16(vf, pfr, oacc[dt], 0, 0, 0);
            }
        }
    }

    // ---- epilogue: store UNNORMALIZED partial O^T and (m, l) ----
    const size_t row = (size_t)s * (B_ * LQ_) + b * LQ_ + q0 + c31;
    float* op = OP + row * D_;
#pragma unroll
    for (int dt = 0; dt < 2; ++dt)
#pragma unroll
        for (int g = 0; g < 4; ++g) {
            f32x4 v;
#pragma unroll
            for (int j = 0; j < 4; ++j) v[j] = oacc[dt][4 * g + j];
            *(f32x4*)(op + dt * 32 + 8 * g + 4 * h) = v;
        }
    if (h == 0)
        *(float2*)&ML[row * 2] = float2{mrun, lrun};   // (-inf, 0) if empty split
}

// ---------------------------------------------------------------------------
// Pass 2: merge NS partials per q row. One thread per (row, 4-dim chunk).
// ---------------------------------------------------------------------------
template<int NS>
__global__ __launch_bounds__(256) void fa_merge_kernel(
    const float* __restrict__ OP, const float* __restrict__ ML,
    float* __restrict__ O)
{
    const int g   = blockIdx.x * 256 + threadIdx.x;   // 0 .. B*LQ*16-1
    const int row = g >> 4;                            // b*LQ + q
    const int qd  = (g & 15) * 4;

    float mf = -INFINITY;
#pragma unroll
    for (int s = 0; s < NS; ++s) {
        float2 ml = *(const float2*)&ML[((size_t)s * (B_ * LQ_) + row) * 2];
        mf = fmaxf(mf, ml.x);                          // split 0 always finite
    }
    float den = 0.f;
    f32x4 acc = {0.f, 0.f, 0.f, 0.f};
#pragma unroll
    for (int s = 0; s < NS; ++s) {
        const size_t srow = (size_t)s * (B_ * LQ_) + row;
        float2 ml = *(const float2*)&ML[srow * 2];
        const float c = exp2f(ml.x - mf);              // 0 for empty splits
        den += c * ml.y;
        f32x4 v = *(const f32x4*)&OP[srow * D_ + qd];
        acc += v * c;                                  // empty split: c=0, v=0
    }
    const float inv = 1.f / den;
    *(f32x4*)(O + (size_t)row * D_ + qd) = acc * inv;
}

// ---------------------------------------------------------------------------
// Fallback: monolithic kernel (round-3 structure + defer-max), no workspace.
// ---------------------------------------------------------------------------
__global__ __launch_bounds__(128, 2) void fa_mono_kernel(
    const float* __restrict__ Q, const float* __restrict__ K,
    const float* __restrict__ V, const int* __restrict__ vlen,
    float* __restrict__ O)
{
    __shared__ __align__(16) short Kl[2][64 * 64];
    __shared__ __align__(16) short Vt[2][64 * 64];

    const int tid  = threadIdx.x;
    const int wave = tid >> 6;
    const int lane = tid & 63;
    const int c31  = lane & 31;
    const int h    = lane >> 5;

    const int b  = blockIdx.y;
    const int q0 = blockIdx.x * 64 + wave * 32;
    const int vl = vlen[b];
    const int nt = (vl + 63) >> 6;

    const float qscale = 0.125f * 1.44269504088896340736f;

    unsigned qfrag[4][4];
#pragma unroll
    for (int ks = 0; ks < 4; ++ks) {
        const float* qp = Q + ((size_t)(b * LQ_ + q0 + c31)) * D_ + ks * 16 + h * 8;
        f32x4 t0 = *(const f32x4*)qp;
        f32x4 t1 = *(const f32x4*)(qp + 4);
#pragma unroll
        for (int jj = 0; jj < 2; ++jj) {
            qfrag[ks][jj]     = pk_bf16(t0[2*jj] * qscale, t0[2*jj+1] * qscale);
            qfrag[ks][jj + 2] = pk_bf16(t1[2*jj] * qscale, t1[2*jj+1] * qscale);
        }
    }

    f32x16 oacc[2];
#pragma unroll
    for (int dt = 0; dt < 2; ++dt)
#pragma unroll
        for (int r = 0; r < 16; ++r) oacc[dt][r] = 0.f;
    float mrun = -INFINITY, lrun = 0.f;

    const int skey = tid >> 1, skh = tid & 1;
    const int vkg = tid >> 4, vdg = tid & 15;

    const float* kgp = K + ((size_t)(b * LK_ + skey)) * D_ + skh * 32;
    const float* vgp = V + ((size_t)(b * LK_ + vkg * 8)) * D_ + vdg * 4;

    f32x4 kr[8], vr[8];
#pragma unroll
    for (int i = 0; i < 8; ++i) kr[i] = *(const f32x4*)(kgp + 4 * i);
#pragma unroll
    for (int i = 0; i < 8; ++i) vr[i] = *(const f32x4*)(vgp + (size_t)i * D_);

    for (int t = 0; t < nt; ++t) {
        const int k0 = t * 64;
        const int buf = t & 1;
        {
            unsigned pk32[16];
#pragma unroll
            for (int m = 0; m < 16; ++m)
                pk32[m] = pk_bf16(kr[m >> 1][2 * (m & 1)], kr[m >> 1][2 * (m & 1) + 1]);
#pragma unroll
            for (int cch = 0; cch < 4; ++cch) {
                const int pos = (skh * 4 + cch) ^ (skey & 7);
                *(bf16x8*)&Kl[buf][skey * 64 + pos * 8] = *(bf16x8*)&pk32[4 * cch];
            }
#pragma unroll
            for (int dr = 0; dr < 4; ++dr) {
                unsigned w[4];
#pragma unroll
                for (int p = 0; p < 4; ++p)
                    w[p] = pk_bf16(vr[2 * p][dr], vr[2 * p + 1][dr]);
                const int dim = vdg * 4 + dr;
                const int pos = vkg ^ (dim & 7);
                *(bf16x8*)&Vt[buf][dim * 64 + pos * 8] = *(bf16x8*)&w[0];
            }
        }
        if (t + 1 < nt) {
            const float* kn = kgp + (size_t)(k0 + 64) * D_;
            const float* vn = vgp + (size_t)(k0 + 64) * D_;
#pragma unroll
            for (int i = 0; i < 8; ++i) kr[i] = *(const f32x4*)(kn + 4 * i);
#pragma unroll
            for (int i = 0; i < 8; ++i) vr[i] = *(const f32x4*)(vn + (size_t)i * D_);
        }
        __syncthreads();

        f32x16 st[2];
#pragma unroll
        for (int ss = 0; ss < 2; ++ss) {
#pragma unroll
            for (int r = 0; r < 16; ++r) st[ss][r] = 0.f;
#pragma unroll
            for (int ks = 0; ks < 4; ++ks) {
                const int pos = (ks * 2 + h) ^ (c31 & 7);
                bf16x8 kf = *(const bf16x8*)&Kl[buf][(ss * 32 + c31) * 64 + pos * 8];
                st[ss] = __builtin_amdgcn_mfma_f32_32x32x16_bf16(
                    kf, *(const bf16x8*)&qfrag[ks][0], st[ss], 0, 0, 0);
            }
        }
        if (k0 + 64 > vl) {
#pragma unroll
            for (int ss = 0; ss < 2; ++ss) {
                const int base = k0 + ss * 32 + 4 * h;
#pragma unroll
                for (int r = 0; r < 16; ++r) {
                    const int key = base + (r & 3) + 8 * (r >> 2);
                    if (key >= vl) st[ss][r] = -1e30f;
                }
            }
        }
        float tm = st[0][0];
#pragma unroll
        for (int ss = 0; ss < 2; ++ss)
#pragma unroll
            for (int r = 0; r < 16; ++r) tm = fmaxf(tm, st[ss][r]);
        tm = fmaxf(tm, __shfl_xor(tm, 32));
        if (__any(tm > mrun + 8.f)) {
            const float mnew = fmaxf(mrun, tm);
            const float corr = exp2f(mrun - mnew);
            lrun *= corr;
#pragma unroll
            for (int dt = 0; dt < 2; ++dt)
#pragma unroll
                for (int r = 0; r < 16; ++r) oacc[dt][r] *= corr;
            mrun = mnew;
        }
        float rs = 0.f;
#pragma unroll
        for (int ss = 0; ss < 2; ++ss)
#pragma unroll
            for (int r = 0; r < 16; ++r) {
                const float p = exp2f(st[ss][r] - mrun);
                st[ss][r] = p;
                rs += p;
            }
        rs += __shfl_xor(rs, 32);
        lrun += rs;

        unsigned pk[2][8];
#pragma unroll
        for (int ss = 0; ss < 2; ++ss)
#pragma unroll
            for (int m = 0; m < 8; ++m)
                pk[ss][m] = pk_bf16(st[ss][2 * m], st[ss][2 * m + 1]);
#pragma unroll
        for (int kq = 0; kq < 4; ++kq) {
            const int ss = kq >> 1, A4 = (kq & 1) * 4;
            unsigned p0 = pk[ss][A4], p1 = pk[ss][A4+1], p2 = pk[ss][A4+2], p3 = pk[ss][A4+3];
            unsigned xp0 = __shfl_xor((int)p0, 32);
            unsigned xp1 = __shfl_xor((int)p1, 32);
            unsigned xp2 = __shfl_xor((int)p2, 32);
            unsigned xp3 = __shfl_xor((int)p3, 32);
            unsigned pf[4];
            pf[0] = h ? xp2 : p0;
            pf[1] = h ? xp3 : p1;
            pf[2] = h ? p2  : xp0;
            pf[3] = h ? p3  : xp1;
            const bf16x8 pfr = *(const bf16x8*)&pf[0];
#pragma unroll
            for (int dt = 0; dt < 2; ++dt) {
                const int pos = (kq * 2 + h) ^ (c31 & 7);
                bf16x8 vf = *(const bf16x8*)&Vt[buf][(dt * 32 + c31) * 64 + pos * 8];
                oacc[dt] = __builtin_amdgcn_mfma_f32_32x32x16_bf16(vf, pfr, oacc[dt], 0, 0, 0);
            }
        }
    }

    const float inv = 1.f / lrun;
    float* op = O + ((size_t)(b * LQ_ + q0 + c31)) * D_;
#pragma unroll
    for (int dt = 0; dt < 2; ++dt)
#pragma unroll
        for (int g = 0; g < 4; ++g) {
            f32x4 v;
#pragma unroll
            for (int j = 0; j < 4; ++j) v[j] = oacc[dt][4 * g + j] * inv;
            *(f32x4*)(op + dt * 32 + 8 * g + 4 * h) = v;
        }
}

extern "C" void kernel_launch(void* const* d_in, const int* in_sizes, int n_in,
                              void* d_out, int out_size, void* d_ws, size_t ws_size,
                              hipStream_t stream) {
    const float* Q    = (const float*)d_in[0];
    const float* K    = (const float*)d_in[1];
    const float* V    = (const float*)d_in[2];
    const int*   vlen = (const int*)d_in[3];
    float*       O    = (float*)d_out;

    const size_t rows = (size_t)B_ * LQ_;
    auto need = [&](int ns) { return (size_t)ns * rows * (D_ + 2) * sizeof(float); };

    int NS = 0;
    if      (d_ws && ws_size >= need(4)) NS = 4;
    else if (d_ws && ws_size >= need(2)) NS = 2;
    else if (d_ws && ws_size >= need(1)) NS = 1;

    if (NS == 0) {
        dim3 grid(LQ_ / 64, B_);
        fa_mono_kernel<<<grid, dim3(128), 0, stream>>>(Q, K, V, vlen, O);
        return;
    }

    float* OP = (float*)d_ws;
    float* ML = (float*)d_ws + (size_t)NS * rows * D_;

    const unsigned nblk = (unsigned)(16 * B_ * NS);   // 1D, LPT-ordered
    switch (NS) {
        case 4: fa_split10_kernel<4><<<dim3(nblk), dim3(256), 0, stream>>>(Q, K, V, vlen, OP, ML); break;
        case 2: fa_split10_kernel<2><<<dim3(nblk), dim3(256), 0, stream>>>(Q, K, V, vlen, OP, ML); break;
        default: fa_split10_kernel<1><<<dim3(nblk), dim3(256), 0, stream>>>(Q, K, V, vlen, OP, ML); break;
    }

    dim3 g2((unsigned)((rows * (D_ / 4)) / 256));   // 4096 blocks
    switch (NS) {
        case 4: fa_merge_kernel<4><<<g2, dim3(256), 0, stream>>>(OP, ML, O); break;
        case 2: fa_merge_kernel<2><<<g2, dim3(256), 0, stream>>>(OP, ML, O); break;
        default: fa_merge_kernel<1><<<g2, dim3(256), 0, stream>>>(OP, ML, O); break;
    }
}

// Round 16
// 151.127 us; speedup vs baseline: 1.3899x; 1.0678x over previous
//
#include <hip/hip_runtime.h>
#include <hip/hip_bf16.h>
#include <math.h>

// Masked dot-product attention, bf16 MFMA flash kernel, round 19.
// B=32, LQ=LK=2048, D=64. S^T = K*Q^T and O^T = V^T*P^T with 32x32x16 MFMA.
// = r15 proven base (LDS-staged split, prefetch-after-barrier, (256,2)) +
//   pre-converted bf16 K/V staging (hybrid of r15 and r16's cvt pass).
//  - r18 post-mortem: (256,6) made LLVM abandon the cap (VGPR 112, occupancy
//    18%, 75us). REVERTED. Key insight: at 84 VGPR the cap was already
//    6 waves/SIMD; we run at ~1/3 of cap in all configs -> occupancy cap is
//    NOT the limiter. VALU (51%) is the busiest pipe.
//  - This round: remove the per-tile staging convert (16 cvt_pk + f32 addr
//    math, repeated by 16 q-blocks per (batch,tile)). fa_cvt_kernel (proven
//    in r17, refcheck'd) converts K->Kb bf16 and V->Vtb bf16-transposed once;
//    split stages 4x16B bf16 loads + 4 ds_write_b128, layout byte-identical
//    (chunk c of row r at pos c^(r&7); read side unchanged).
//  - Falsifiable: split FETCH ~45MB, VALUBusy down, split <60us; else plateau.

#define B_    32
#define LQ_   2048
#define LK_   2048
#define D_    64

typedef __attribute__((ext_vector_type(8)))  short bf16x8;
typedef __attribute__((ext_vector_type(4)))  float f32x4;
typedef __attribute__((ext_vector_type(16))) float f32x16;
typedef __attribute__((ext_vector_type(2)))  unsigned u32x2;

static __device__ __forceinline__ unsigned pk_bf16(float a, float b) {
    __hip_bfloat162 h = __float22bfloat162_rn(float2{a, b});
    return *(unsigned*)&h;   // x in low 16 bits, y in high
}

static __device__ __forceinline__ u32x2 plswap(unsigned a, unsigned b) {
    return __builtin_amdgcn_permlane32_swap(a, b, false, false);
}
static __device__ __forceinline__ float xhalf_max(float x) {
    u32x2 r = plswap(__float_as_uint(x), __float_as_uint(x));
    return fmaxf(__uint_as_float(r[0]), __uint_as_float(r[1]));
}
static __device__ __forceinline__ float xhalf_add(float x) {
    u32x2 r = plswap(__float_as_uint(x), __float_as_uint(x));
    return __uint_as_float(r[0]) + __uint_as_float(r[1]);
}

// ---------------------------------------------------------------------------
// Pass 0 (proven in r17): K (f32 [b][k][d]) -> Kb (bf16 [b][k][d]);
//                         V (f32 [b][k][d]) -> Vtb (bf16 [b][d][k]).
// ---------------------------------------------------------------------------
__global__ __launch_bounds__(256) void fa_cvt_kernel(
    const float* __restrict__ K, const float* __restrict__ V,
    short* __restrict__ Kb, short* __restrict__ Vtb)
{
    const int tid = threadIdx.x;
    const int b   = blockIdx.y;
    const int k0  = blockIdx.x * 64;

    {
        const int kk = tid >> 2, q4 = tid & 3;
        const size_t off = ((size_t)(b * LK_ + k0 + kk)) * D_ + q4 * 16;
        const float* src = K + off;
        unsigned w[8];
#pragma unroll
        for (int i = 0; i < 4; ++i) {
            f32x4 v = *(const f32x4*)(src + 4 * i);
            w[2 * i]     = pk_bf16(v[0], v[1]);
            w[2 * i + 1] = pk_bf16(v[2], v[3]);
        }
        short* dst = Kb + off;
        *(bf16x8*)dst       = *(bf16x8*)&w[0];
        *(bf16x8*)(dst + 8) = *(bf16x8*)&w[4];
    }
    {
        const int vkg = tid & 15, vdg = tid >> 4;
        f32x4 vv[4];
#pragma unroll
        for (int p = 0; p < 4; ++p)
            vv[p] = *(const f32x4*)&V[((size_t)(b * LK_ + k0 + vkg * 4 + p)) * D_ + vdg * 4];
#pragma unroll
        for (int dr = 0; dr < 4; ++dr) {
            uint2 w = { pk_bf16(vv[0][dr], vv[1][dr]), pk_bf16(vv[2][dr], vv[3][dr]) };
            *(uint2*)&Vtb[((size_t)(b * 64 + vdg * 4 + dr)) * LK_ + k0 + vkg * 4] = w;
        }
    }
}

// ---------------------------------------------------------------------------
// Pass 1: LDS-staged split kernel, staging FROM pre-converted bf16 buffers.
// 256 threads = 4 q-waves sharing one double-buffered 64x64 K/V LDS tile.
// LPT: blockIdx.x -> (batch_rank, qblock, split), rank via shfl+ballot.
// Writes UNNORMALIZED O^T partial + (m, l) per q row.
// ---------------------------------------------------------------------------
template<int NS>
__global__ __launch_bounds__(256, 2) void fa_split11_kernel(
    const float* __restrict__ Q, const short* __restrict__ Kb,
    const short* __restrict__ Vtb, const int* __restrict__ vlen,
    float* __restrict__ OP, float* __restrict__ ML)
{
    __shared__ __align__(16) short Kl[2][64 * 64];
    __shared__ __align__(16) short Vt[2][64 * 64];

    const int tid  = threadIdx.x;          // 0..255
    const int wid  = tid >> 6;             // 0..3  (q sub-block)
    const int lane = tid & 63;
    const int c31  = lane & 31;
    const int h    = lane >> 5;

    // ---- LPT remap (LDS-free): rank batches by vl DESC, index tie-break ----
    constexpr int PB = 16 * NS;            // blocks per batch
    const int L    = blockIdx.x;
    const int rank = L / PB;
    const int sub  = L % PB;
    const int qb   = sub & 15;
    const int s    = sub >> 4;
    int b;
    {
        const int vj = vlen[c31];          // lanes j and j+32 hold vlen[j]
        int r = 0;
#pragma unroll
        for (int k = 0; k < 32; ++k) {
            const int vk = __shfl(vj, k);
            r += (vk > vj) || (vk == vj && k < c31);
        }
        const unsigned long long match = __ballot(r == rank);
        b = (int)(__ffsll(match) - 1) & 31;
    }
    const int q0 = qb * 128 + wid * 32;
    const int vl = vlen[b];
    const int nt    = (vl + 63) >> 6;
    const int chunk = (nt + NS - 1) / NS;
    const int t0    = s * chunk;
    const int t1    = min(t0 + chunk, nt);

    const float qscale = 0.125f * 1.44269504088896340736f;  // 1/sqrt(64)*log2(e)

    // ---- Q B-frags in registers: B[k=dim][n=q], dim = ks*16 + h*8 + j ----
    unsigned qfrag[4][4];
#pragma unroll
    for (int ks = 0; ks < 4; ++ks) {
        const float* qp = Q + ((size_t)(b * LQ_ + q0 + c31)) * D_ + ks * 16 + h * 8;
        f32x4 t0v = *(const f32x4*)qp;
        f32x4 t1v = *(const f32x4*)(qp + 4);
#pragma unroll
        for (int jj = 0; jj < 2; ++jj) {
            qfrag[ks][jj]     = pk_bf16(t0v[2*jj] * qscale, t0v[2*jj+1] * qscale);
            qfrag[ks][jj + 2] = pk_bf16(t1v[2*jj] * qscale, t1v[2*jj+1] * qscale);
        }
    }

    f32x16 oacc[2];     // O^T acc: dim row = dt*32 + (r&3)+8*(r>>2)+4h, col q = c31
#pragma unroll
    for (int dt = 0; dt < 2; ++dt)
#pragma unroll
        for (int r = 0; r < 16; ++r) oacc[dt][r] = 0.f;
    float mrun = -INFINITY, lrun = 0.f;

    // ---- staging maps: 256 threads x 32B = 8KB bf16 tile each for K and V ----
    // K: row skey (0..63), quarter skh (0..3) -> chunks skh*2, skh*2+1.
    const int skey = tid >> 2, skh = tid & 3;
    // V^T: row vdim (0..63), quarter vkh (0..3) -> chunks vkh*2, vkh*2+1.
    const int vdim = skey, vkh = skh;

    const short* kbp = Kb  + ((size_t)(b * LK_ + skey)) * D_ + skh * 16;
    const short* vtp = Vtb + ((size_t)(b * 64 + vdim)) * LK_ + vkh * 16;

    bf16x8 kr0, kr1, vr0, vr1;
    // ---- prologue: prefetch tile t0 into registers ----
    if (t0 < t1) {
        const short* kp = kbp + (size_t)t0 * 64 * D_;
        const short* vp = vtp + (size_t)t0 * 64;
        kr0 = *(const bf16x8*)(kp);
        kr1 = *(const bf16x8*)(kp + 8);
        vr0 = *(const bf16x8*)(vp);
        vr1 = *(const bf16x8*)(vp + 8);
    }

    for (int t = t0; t < t1; ++t) {
        const int k0 = t * 64;
        const int buf = t & 1;

        // ---- write tile t to LDS (chunk c of row r at pos c^(r&7)) ----
        {
            const int pk0 = (skh * 2)     ^ (skey & 7);
            const int pk1 = (skh * 2 + 1) ^ (skey & 7);
            *(bf16x8*)&Kl[buf][skey * 64 + pk0 * 8] = kr0;
            *(bf16x8*)&Kl[buf][skey * 64 + pk1 * 8] = kr1;
            const int pv0 = (vkh * 2)     ^ (vdim & 7);
            const int pv1 = (vkh * 2 + 1) ^ (vdim & 7);
            *(bf16x8*)&Vt[buf][vdim * 64 + pv0 * 8] = vr0;
            *(bf16x8*)&Vt[buf][vdim * 64 + pv1 * 8] = vr1;
        }
        __syncthreads();

        // ---- issue prefetch for tile t+1 (flies under the compute phase) ----
        if (t + 1 < t1) {
            const short* kp = kbp + (size_t)(k0 + 64) * D_;
            const short* vp = vtp + (size_t)(k0 + 64);
            kr0 = *(const bf16x8*)(kp);
            kr1 = *(const bf16x8*)(kp + 8);
            vr0 = *(const bf16x8*)(vp);
            vr1 = *(const bf16x8*)(vp + 8);
        }

        // ---- S^T = K * Q^T : 2 key-tiles x 4 k-steps of 32x32x16 ----
        f32x16 st[2];
#pragma unroll
        for (int ss = 0; ss < 2; ++ss) {
#pragma unroll
            for (int r = 0; r < 16; ++r) st[ss][r] = 0.f;
#pragma unroll
            for (int ks = 0; ks < 4; ++ks) {
                const int pos = (ks * 2 + h) ^ (c31 & 7);
                bf16x8 kf = *(const bf16x8*)&Kl[buf][(ss * 32 + c31) * 64 + pos * 8];
                st[ss] = __builtin_amdgcn_mfma_f32_32x32x16_bf16(
                    kf, *(const bf16x8*)&qfrag[ks][0], st[ss], 0, 0, 0);
            }
        }

        // ---- mask tail keys >= vl ----
        if (k0 + 64 > vl) {
#pragma unroll
            for (int ss = 0; ss < 2; ++ss) {
                const int base = k0 + ss * 32 + 4 * h;
#pragma unroll
                for (int r = 0; r < 16; ++r) {
                    const int key = base + (r & 3) + 8 * (r >> 2);
                    if (key >= vl) st[ss][r] = -1e30f;
                }
            }
        }

        // ---- online softmax (log2 domain), defer-max; tree reductions ----
        float m8[8];
#pragma unroll
        for (int r = 0; r < 8; ++r)
            m8[r] = fmaxf(fmaxf(st[0][r], st[0][r + 8]),
                          fmaxf(st[1][r], st[1][r + 8]));
#pragma unroll
        for (int o = 4; o; o >>= 1)
#pragma unroll
            for (int r = 0; r < o; ++r) m8[r] = fmaxf(m8[r], m8[r + o]);
        const float tm = xhalf_max(m8[0]);

        if (__any(tm > mrun + 8.f)) {          // rare after the first tile
            const float mnew = fmaxf(mrun, tm);
            const float corr = exp2f(mrun - mnew);
            lrun *= corr;
#pragma unroll
            for (int dt = 0; dt < 2; ++dt)
#pragma unroll
                for (int r = 0; r < 16; ++r) oacc[dt][r] *= corr;
            mrun = mnew;
        }
#pragma unroll
        for (int ss = 0; ss < 2; ++ss)
#pragma unroll
            for (int r = 0; r < 16; ++r)
                st[ss][r] = exp2f(st[ss][r] - mrun);   // bounded by 2^8
        float s8[8];
#pragma unroll
        for (int r = 0; r < 8; ++r)
            s8[r] = (st[0][r] + st[0][r + 8]) + (st[1][r] + st[1][r + 8]);
#pragma unroll
        for (int o = 4; o; o >>= 1)
#pragma unroll
            for (int r = 0; r < o; ++r) s8[r] += s8[r + o];
        lrun += xhalf_add(s8[0]);

        // ---- pack P to bf16 pairs ----
        unsigned pk[2][8];
#pragma unroll
        for (int ss = 0; ss < 2; ++ss)
#pragma unroll
            for (int m = 0; m < 8; ++m)
                pk[ss][m] = pk_bf16(st[ss][2 * m], st[ss][2 * m + 1]);

        // ---- O^T += V^T * P^T : 4 k-steps x 2 dim-tiles ----
#pragma unroll
        for (int kq = 0; kq < 4; ++kq) {
            const int ss = kq >> 1, A4 = (kq & 1) * 4;
            u32x2 r02 = plswap(pk[ss][A4],     pk[ss][A4 + 2]);
            u32x2 r13 = plswap(pk[ss][A4 + 1], pk[ss][A4 + 3]);
            unsigned pf[4] = {r02[0], r13[0], r02[1], r13[1]};
            const bf16x8 pfr = *(const bf16x8*)&pf[0];
#pragma unroll
            for (int dt = 0; dt < 2; ++dt) {
                const int pos = (kq * 2 + h) ^ (c31 & 7);
                bf16x8 vf = *(const bf16x8*)&Vt[buf][(dt * 32 + c31) * 64 + pos * 8];
                oacc[dt] = __builtin_amdgcn_mfma_f32_32x32x16_bf16(vf, pfr, oacc[dt], 0, 0, 0);
            }
        }
    }

    // ---- epilogue: store UNNORMALIZED partial O^T and (m, l) ----
    const size_t row = (size_t)s * (B_ * LQ_) + b * LQ_ + q0 + c31;
    float* op = OP + row * D_;
#pragma unroll
    for (int dt = 0; dt < 2; ++dt)
#pragma unroll
        for (int g = 0; g < 4; ++g) {
            f32x4 v;
#pragma unroll
            for (int j = 0; j < 4; ++j) v[j] = oacc[dt][4 * g + j];
            *(f32x4*)(op + dt * 32 + 8 * g + 4 * h) = v;
        }
    if (h == 0)
        *(float2*)&ML[row * 2] = float2{mrun, lrun};   // (-inf, 0) if empty split
}

// ---------------------------------------------------------------------------
// Pass 2: merge NS partials per q row. One thread per (row, 4-dim chunk).
// ---------------------------------------------------------------------------
template<int NS>
__global__ __launch_bounds__(256) void fa_merge_kernel(
    const float* __restrict__ OP, const float* __restrict__ ML,
    float* __restrict__ O)
{
    const int g   = blockIdx.x * 256 + threadIdx.x;   // 0 .. B*LQ*16-1
    const int row = g >> 4;                            // b*LQ + q
    const int qd  = (g & 15) * 4;

    float mf = -INFINITY;
#pragma unroll
    for (int s = 0; s < NS; ++s) {
        float2 ml = *(const float2*)&ML[((size_t)s * (B_ * LQ_) + row) * 2];
        mf = fmaxf(mf, ml.x);                          // split 0 always finite
    }
    float den = 0.f;
    f32x4 acc = {0.f, 0.f, 0.f, 0.f};
#pragma unroll
    for (int s = 0; s < NS; ++s) {
        const size_t srow = (size_t)s * (B_ * LQ_) + row;
        float2 ml = *(const float2*)&ML[srow * 2];
        const float c = exp2f(ml.x - mf);              // 0 for empty splits
        den += c * ml.y;
        f32x4 v = *(const f32x4*)&OP[srow * D_ + qd];
        acc += v * c;                                  // empty split: c=0, v=0
    }
    const float inv = 1.f / den;
    *(f32x4*)(O + (size_t)row * D_ + qd) = acc * inv;
}

// ---------------------------------------------------------------------------
// Fallback A: r15 proven split kernel (f32 inputs, in-loop cvt, 66us).
// ---------------------------------------------------------------------------
template<int NS>
__global__ __launch_bounds__(256, 2) void fa_split9_kernel(
    const float* __restrict__ Q, const float* __restrict__ K,
    const float* __restrict__ V, const int* __restrict__ vlen,
    float* __restrict__ OP, float* __restrict__ ML)
{
    __shared__ __align__(16) short Kl[2][64 * 64];
    __shared__ __align__(16) short Vt[2][64 * 64];

    const int tid  = threadIdx.x;
    const int wid  = tid >> 6;
    const int lane = tid & 63;
    const int c31  = lane & 31;
    const int h    = lane >> 5;

    constexpr int PB = 16 * NS;
    const int L    = blockIdx.x;
    const int rank = L / PB;
    const int sub  = L % PB;
    const int qb   = sub & 15;
    const int s    = sub >> 4;
    int b;
    {
        const int vj = vlen[c31];
        int r = 0;
#pragma unroll
        for (int k = 0; k < 32; ++k) {
            const int vk = __shfl(vj, k);
            r += (vk > vj) || (vk == vj && k < c31);
        }
        const unsigned long long match = __ballot(r == rank);
        b = (int)(__ffsll(match) - 1) & 31;
    }
    const int q0 = qb * 128 + wid * 32;
    const int vl = vlen[b];
    const int nt    = (vl + 63) >> 6;
    const int chunk = (nt + NS - 1) / NS;
    const int t0    = s * chunk;
    const int t1    = min(t0 + chunk, nt);

    const float qscale = 0.125f * 1.44269504088896340736f;

    unsigned qfrag[4][4];
#pragma unroll
    for (int ks = 0; ks < 4; ++ks) {
        const float* qp = Q + ((size_t)(b * LQ_ + q0 + c31)) * D_ + ks * 16 + h * 8;
        f32x4 t0v = *(const f32x4*)qp;
        f32x4 t1v = *(const f32x4*)(qp + 4);
#pragma unroll
        for (int jj = 0; jj < 2; ++jj) {
            qfrag[ks][jj]     = pk_bf16(t0v[2*jj] * qscale, t0v[2*jj+1] * qscale);
            qfrag[ks][jj + 2] = pk_bf16(t1v[2*jj] * qscale, t1v[2*jj+1] * qscale);
        }
    }

    f32x16 oacc[2];
#pragma unroll
    for (int dt = 0; dt < 2; ++dt)
#pragma unroll
        for (int r = 0; r < 16; ++r) oacc[dt][r] = 0.f;
    float mrun = -INFINITY, lrun = 0.f;

    const int skey = tid >> 2, skh = tid & 3;
    const int vkg = tid >> 4, vdg = tid & 15;

    const float* kgp = K + ((size_t)(b * LK_ + skey)) * D_ + skh * 16;
    const float* vgp = V + ((size_t)(b * LK_ + vkg * 4)) * D_ + vdg * 4;

    f32x4 kr[4], vr[4];
    if (t0 < t1) {
        const size_t off = (size_t)t0 * 64 * D_;
#pragma unroll
        for (int i = 0; i < 4; ++i) kr[i] = *(const f32x4*)(kgp + off + 4 * i);
#pragma unroll
        for (int i = 0; i < 4; ++i) vr[i] = *(const f32x4*)(vgp + off + (size_t)i * D_);
    }

    for (int t = t0; t < t1; ++t) {
        const int k0 = t * 64;
        const int buf = t & 1;
        {
            unsigned pk32[8];
#pragma unroll
            for (int m = 0; m < 8; ++m)
                pk32[m] = pk_bf16(kr[m >> 1][2 * (m & 1)], kr[m >> 1][2 * (m & 1) + 1]);
#pragma unroll
            for (int cch = 0; cch < 2; ++cch) {
                const int pos = (skh * 2 + cch) ^ (skey & 7);
                *(bf16x8*)&Kl[buf][skey * 64 + pos * 8] = *(bf16x8*)&pk32[4 * cch];
            }
#pragma unroll
            for (int dr = 0; dr < 4; ++dr) {
                const unsigned w0 = pk_bf16(vr[0][dr], vr[1][dr]);
                const unsigned w1 = pk_bf16(vr[2][dr], vr[3][dr]);
                const int dim = vdg * 4 + dr;
                const int pos = (vkg >> 1) ^ (dim & 7);
                *(uint2*)&Vt[buf][dim * 64 + pos * 8 + (vkg & 1) * 4] = uint2{w0, w1};
            }
        }
        __syncthreads();
        if (t + 1 < t1) {
            const float* kn = kgp + (size_t)(k0 + 64) * D_;
            const float* vn = vgp + (size_t)(k0 + 64) * D_;
#pragma unroll
            for (int i = 0; i < 4; ++i) kr[i] = *(const f32x4*)(kn + 4 * i);
#pragma unroll
            for (int i = 0; i < 4; ++i) vr[i] = *(const f32x4*)(vn + (size_t)i * D_);
        }

        f32x16 st[2];
#pragma unroll
        for (int ss = 0; ss < 2; ++ss) {
#pragma unroll
            for (int r = 0; r < 16; ++r) st[ss][r] = 0.f;
#pragma unroll
            for (int ks = 0; ks < 4; ++ks) {
                const int pos = (ks * 2 + h) ^ (c31 & 7);
                bf16x8 kf = *(const bf16x8*)&Kl[buf][(ss * 32 + c31) * 64 + pos * 8];
                st[ss] = __builtin_amdgcn_mfma_f32_32x32x16_bf16(
                    kf, *(const bf16x8*)&qfrag[ks][0], st[ss], 0, 0, 0);
            }
        }
        if (k0 + 64 > vl) {
#pragma unroll
            for (int ss = 0; ss < 2; ++ss) {
                const int base = k0 + ss * 32 + 4 * h;
#pragma unroll
                for (int r = 0; r < 16; ++r) {
                    const int key = base + (r & 3) + 8 * (r >> 2);
                    if (key >= vl) st[ss][r] = -1e30f;
                }
            }
        }
        float m8[8];
#pragma unroll
        for (int r = 0; r < 8; ++r)
            m8[r] = fmaxf(fmaxf(st[0][r], st[0][r + 8]),
                          fmaxf(st[1][r], st[1][r + 8]));
#pragma unroll
        for (int o = 4; o; o >>= 1)
#pragma unroll
            for (int r = 0; r < o; ++r) m8[r] = fmaxf(m8[r], m8[r + o]);
        const float tm = xhalf_max(m8[0]);
        if (__any(tm > mrun + 8.f)) {
            const float mnew = fmaxf(mrun, tm);
            const float corr = exp2f(mrun - mnew);
            lrun *= corr;
#pragma unroll
            for (int dt = 0; dt < 2; ++dt)
#pragma unroll
                for (int r = 0; r < 16; ++r) oacc[dt][r] *= corr;
            mrun = mnew;
        }
#pragma unroll
        for (int ss = 0; ss < 2; ++ss)
#pragma unroll
            for (int r = 0; r < 16; ++r)
                st[ss][r] = exp2f(st[ss][r] - mrun);
        float s8[8];
#pragma unroll
        for (int r = 0; r < 8; ++r)
            s8[r] = (st[0][r] + st[0][r + 8]) + (st[1][r] + st[1][r + 8]);
#pragma unroll
        for (int o = 4; o; o >>= 1)
#pragma unroll
            for (int r = 0; r < o; ++r) s8[r] += s8[r + o];
        lrun += xhalf_add(s8[0]);

        unsigned pk[2][8];
#pragma unroll
        for (int ss = 0; ss < 2; ++ss)
#pragma unroll
            for (int m = 0; m < 8; ++m)
                pk[ss][m] = pk_bf16(st[ss][2 * m], st[ss][2 * m + 1]);
#pragma unroll
        for (int kq = 0; kq < 4; ++kq) {
            const int ss = kq >> 1, A4 = (kq & 1) * 4;
            u32x2 r02 = plswap(pk[ss][A4],     pk[ss][A4 + 2]);
            u32x2 r13 = plswap(pk[ss][A4 + 1], pk[ss][A4 + 3]);
            unsigned pf[4] = {r02[0], r13[0], r02[1], r13[1]};
            const bf16x8 pfr = *(const bf16x8*)&pf[0];
#pragma unroll
            for (int dt = 0; dt < 2; ++dt) {
                const int pos = (kq * 2 + h) ^ (c31 & 7);
                bf16x8 vfv = *(const bf16x8*)&Vt[buf][(dt * 32 + c31) * 64 + pos * 8];
                oacc[dt] = __builtin_amdgcn_mfma_f32_32x32x16_bf16(vfv, pfr, oacc[dt], 0, 0, 0);
            }
        }
    }

    const size_t row = (size_t)s * (B_ * LQ_) + b * LQ_ + q0 + c31;
    float* op = OP + row * D_;
#pragma unroll
    for (int dt = 0; dt < 2; ++dt)
#pragma unroll
        for (int g = 0; g < 4; ++g) {
            f32x4 v;
#pragma unroll
            for (int j = 0; j < 4; ++j) v[j] = oacc[dt][4 * g + j];
            *(f32x4*)(op + dt * 32 + 8 * g + 4 * h) = v;
        }
    if (h == 0)
        *(float2*)&ML[row * 2] = float2{mrun, lrun};
}

// ---------------------------------------------------------------------------
// Fallback B: monolithic kernel, no workspace.
// ---------------------------------------------------------------------------
__global__ __launch_bounds__(128, 2) void fa_mono_kernel(
    const float* __restrict__ Q, const float* __restrict__ K,
    const float* __restrict__ V, const int* __restrict__ vlen,
    float* __restrict__ O)
{
    __shared__ __align__(16) short Kl[2][64 * 64];
    __shared__ __align__(16) short Vt[2][64 * 64];

    const int tid  = threadIdx.x;
    const int wave = tid >> 6;
    const int lane = tid & 63;
    const int c31  = lane & 31;
    const int h    = lane >> 5;

    const int b  = blockIdx.y;
    const int q0 = blockIdx.x * 64 + wave * 32;
    const int vl = vlen[b];
    const int nt = (vl + 63) >> 6;

    const float qscale = 0.125f * 1.44269504088896340736f;

    unsigned qfrag[4][4];
#pragma unroll
    for (int ks = 0; ks < 4; ++ks) {
        const float* qp = Q + ((size_t)(b * LQ_ + q0 + c31)) * D_ + ks * 16 + h * 8;
        f32x4 t0 = *(const f32x4*)qp;
        f32x4 t1 = *(const f32x4*)(qp + 4);
#pragma unroll
        for (int jj = 0; jj < 2; ++jj) {
            qfrag[ks][jj]     = pk_bf16(t0[2*jj] * qscale, t0[2*jj+1] * qscale);
            qfrag[ks][jj + 2] = pk_bf16(t1[2*jj] * qscale, t1[2*jj+1] * qscale);
        }
    }

    f32x16 oacc[2];
#pragma unroll
    for (int dt = 0; dt < 2; ++dt)
#pragma unroll
        for (int r = 0; r < 16; ++r) oacc[dt][r] = 0.f;
    float mrun = -INFINITY, lrun = 0.f;

    const int skey = tid >> 1, skh = tid & 1;
    const int vkg = tid >> 4, vdg = tid & 15;

    const float* kgp = K + ((size_t)(b * LK_ + skey)) * D_ + skh * 32;
    const float* vgp = V + ((size_t)(b * LK_ + vkg * 8)) * D_ + vdg * 4;

    f32x4 kr[8], vr[8];
#pragma unroll
    for (int i = 0; i < 8; ++i) kr[i] = *(const f32x4*)(kgp + 4 * i);
#pragma unroll
    for (int i = 0; i < 8; ++i) vr[i] = *(const f32x4*)(vgp + (size_t)i * D_);

    for (int t = 0; t < nt; ++t) {
        const int k0 = t * 64;
        const int buf = t & 1;
        {
            unsigned pk32[16];
#pragma unroll
            for (int m = 0; m < 16; ++m)
                pk32[m] = pk_bf16(kr[m >> 1][2 * (m & 1)], kr[m >> 1][2 * (m & 1) + 1]);
#pragma unroll
            for (int cch = 0; cch < 4; ++cch) {
                const int pos = (skh * 4 + cch) ^ (skey & 7);
                *(bf16x8*)&Kl[buf][skey * 64 + pos * 8] = *(bf16x8*)&pk32[4 * cch];
            }
#pragma unroll
            for (int dr = 0; dr < 4; ++dr) {
                unsigned w[4];
#pragma unroll
                for (int p = 0; p < 4; ++p)
                    w[p] = pk_bf16(vr[2 * p][dr], vr[2 * p + 1][dr]);
                const int dim = vdg * 4 + dr;
                const int pos = vkg ^ (dim & 7);
                *(bf16x8*)&Vt[buf][dim * 64 + pos * 8] = *(bf16x8*)&w[0];
            }
        }
        if (t + 1 < nt) {
            const float* kn = kgp + (size_t)(k0 + 64) * D_;
            const float* vn = vgp + (size_t)(k0 + 64) * D_;
#pragma unroll
            for (int i = 0; i < 8; ++i) kr[i] = *(const f32x4*)(kn + 4 * i);
#pragma unroll
            for (int i = 0; i < 8; ++i) vr[i] = *(const f32x4*)(vn + (size_t)i * D_);
        }
        __syncthreads();

        f32x16 st[2];
#pragma unroll
        for (int ss = 0; ss < 2; ++ss) {
#pragma unroll
            for (int r = 0; r < 16; ++r) st[ss][r] = 0.f;
#pragma unroll
            for (int ks = 0; ks < 4; ++ks) {
                const int pos = (ks * 2 + h) ^ (c31 & 7);
                bf16x8 kf = *(const bf16x8*)&Kl[buf][(ss * 32 + c31) * 64 + pos * 8];
                st[ss] = __builtin_amdgcn_mfma_f32_32x32x16_bf16(
                    kf, *(const bf16x8*)&qfrag[ks][0], st[ss], 0, 0, 0);
            }
        }
        if (k0 + 64 > vl) {
#pragma unroll
            for (int ss = 0; ss < 2; ++ss) {
                const int base = k0 + ss * 32 + 4 * h;
#pragma unroll
                for (int r = 0; r < 16; ++r) {
                    const int key = base + (r & 3) + 8 * (r >> 2);
                    if (key >= vl) st[ss][r] = -1e30f;
                }
            }
        }
        float tm = st[0][0];
#pragma unroll
        for (int ss = 0; ss < 2; ++ss)
#pragma unroll
            for (int r = 0; r < 16; ++r) tm = fmaxf(tm, st[ss][r]);
        tm = fmaxf(tm, __shfl_xor(tm, 32));
        if (__any(tm > mrun + 8.f)) {
            const float mnew = fmaxf(mrun, tm);
            const float corr = exp2f(mrun - mnew);
            lrun *= corr;
#pragma unroll
            for (int dt = 0; dt < 2; ++dt)
#pragma unroll
                for (int r = 0; r < 16; ++r) oacc[dt][r] *= corr;
            mrun = mnew;
        }
        float rs = 0.f;
#pragma unroll
        for (int ss = 0; ss < 2; ++ss)
#pragma unroll
            for (int r = 0; r < 16; ++r) {
                const float p = exp2f(st[ss][r] - mrun);
                st[ss][r] = p;
                rs += p;
            }
        rs += __shfl_xor(rs, 32);
        lrun += rs;

        unsigned pk[2][8];
#pragma unroll
        for (int ss = 0; ss < 2; ++ss)
#pragma unroll
            for (int m = 0; m < 8; ++m)
                pk[ss][m] = pk_bf16(st[ss][2 * m], st[ss][2 * m + 1]);
#pragma unroll
        for (int kq = 0; kq < 4; ++kq) {
            const int ss = kq >> 1, A4 = (kq & 1) * 4;
            unsigned p0 = pk[ss][A4], p1 = pk[ss][A4+1], p2 = pk[ss][A4+2], p3 = pk[ss][A4+3];
            unsigned xp0 = __shfl_xor((int)p0, 32);
            unsigned xp1 = __shfl_xor((int)p1, 32);
            unsigned xp2 = __shfl_xor((int)p2, 32);
            unsigned xp3 = __shfl_xor((int)p3, 32);
            unsigned pf[4];
            pf[0] = h ? xp2 : p0;
            pf[1] = h ? xp3 : p1;
            pf[2] = h ? p2  : xp0;
            pf[3] = h ? p3  : xp1;
            const bf16x8 pfr = *(const bf16x8*)&pf[0];
#pragma unroll
            for (int dt = 0; dt < 2; ++dt) {
                const int pos = (kq * 2 + h) ^ (c31 & 7);
                bf16x8 vf = *(const bf16x8*)&Vt[buf][(dt * 32 + c31) * 64 + pos * 8];
                oacc[dt] = __builtin_amdgcn_mfma_f32_32x32x16_bf16(vf, pfr, oacc[dt], 0, 0, 0);
            }
        }
    }

    const float inv = 1.f / lrun;
    float* op = O + ((size_t)(b * LQ_ + q0 + c31)) * D_;
#pragma unroll
    for (int dt = 0; dt < 2; ++dt)
#pragma unroll
        for (int g = 0; g < 4; ++g) {
            f32x4 v;
#pragma unroll
            for (int j = 0; j < 4; ++j) v[j] = oacc[dt][4 * g + j] * inv;
            *(f32x4*)(op + dt * 32 + 8 * g + 4 * h) = v;
        }
}

extern "C" void kernel_launch(void* const* d_in, const int* in_sizes, int n_in,
                              void* d_out, int out_size, void* d_ws, size_t ws_size,
                              hipStream_t stream) {
    const float* Q    = (const float*)d_in[0];
    const float* K    = (const float*)d_in[1];
    const float* V    = (const float*)d_in[2];
    const int*   vlen = (const int*)d_in[3];
    float*       O    = (float*)d_out;

    const size_t rows    = (size_t)B_ * LQ_;
    const size_t kvElems = (size_t)B_ * LK_ * D_;          // per tensor
    auto needP = [&](int ns) { return (size_t)ns * rows * (D_ + 2) * sizeof(float); };
    const size_t needKV = 2 * kvElems * sizeof(short);     // Kb + Vtb (33.6 MB)

    constexpr int NS = 4;

    if (d_ws && ws_size >= needP(NS) + needKV) {
        // ---- hybrid path: cvt once, LDS-staged split from bf16 buffers ----
        float* OP  = (float*)d_ws;
        float* ML  = OP + (size_t)NS * rows * D_;
        short* Kb  = (short*)(ML + (size_t)NS * rows * 2);
        short* Vtb = Kb + kvElems;

        fa_cvt_kernel<<<dim3(LK_ / 64, B_), dim3(256), 0, stream>>>(K, V, Kb, Vtb);

        const unsigned nblk = (unsigned)(16 * B_ * NS);
        fa_split11_kernel<NS><<<dim3(nblk), dim3(256), 0, stream>>>(Q, Kb, Vtb, vlen, OP, ML);

        dim3 g2((unsigned)((rows * (D_ / 4)) / 256));
        fa_merge_kernel<NS><<<g2, dim3(256), 0, stream>>>(OP, ML, O);
        return;
    }

    if (d_ws && ws_size >= needP(NS)) {
        // ---- r15 proven path ----
        float* OP = (float*)d_ws;
        float* ML = OP + (size_t)NS * rows * D_;
        const unsigned nblk = (unsigned)(16 * B_ * NS);
        fa_split9_kernel<NS><<<dim3(nblk), dim3(256), 0, stream>>>(Q, K, V, vlen, OP, ML);
        dim3 g2((unsigned)((rows * (D_ / 4)) / 256));
        fa_merge_kernel<NS><<<g2, dim3(256), 0, stream>>>(OP, ML, O);
        return;
    }

    dim3 grid(LQ_ / 64, B_);
    fa_mono_kernel<<<grid, dim3(128), 0, stream>>>(Q, K, V, vlen, O);
}

// Round 17
// 148.673 us; speedup vs baseline: 1.4128x; 1.0165x over previous
//
#include <hip/hip_runtime.h>
#include <hip/hip_bf16.h>
#include <math.h>

// Masked dot-product attention, bf16 MFMA flash kernel, round 20.
// B=32, LQ=LK=2048, D=64. S^T = K*Q^T and O^T = V^T*P^T with 32x32x16 MFMA.
// = r19 (cvt-once + bf16-staged split, 57.5us, best) + bf16 O-PARTIALS.
//  - r19 post-mortem: hybrid confirmed (split 66->57.5, FETCH 77->43MB,
//    conflicts 6.1M->2.2M). Pipeline now cvt ~18 + split ~57.5 + merge ~13.
//  - This round: OP partials stored as bf16 (rn). Halves split WRITE
//    (67.6->34MB) and merge read (67->34MB). ML stays f32 (m feeds exp2
//    difference). Accuracy: defer-max bounds P<=2^8; partials normalize by
//    same-scale lrun -> ~0.4% relative add'l error, margin 0.0078 vs 0.0297.

#define B_    32
#define LQ_   2048
#define LK_   2048
#define D_    64

typedef __attribute__((ext_vector_type(8)))  short bf16x8;
typedef __attribute__((ext_vector_type(4)))  float f32x4;
typedef __attribute__((ext_vector_type(16))) float f32x16;
typedef __attribute__((ext_vector_type(2)))  unsigned u32x2;

static __device__ __forceinline__ unsigned pk_bf16(float a, float b) {
    __hip_bfloat162 h = __float22bfloat162_rn(float2{a, b});
    return *(unsigned*)&h;   // x in low 16 bits, y in high
}
static __device__ __forceinline__ float bf_lo(unsigned u) {
    return __uint_as_float(u << 16);
}
static __device__ __forceinline__ float bf_hi(unsigned u) {
    return __uint_as_float(u & 0xffff0000u);
}

static __device__ __forceinline__ u32x2 plswap(unsigned a, unsigned b) {
    return __builtin_amdgcn_permlane32_swap(a, b, false, false);
}
static __device__ __forceinline__ float xhalf_max(float x) {
    u32x2 r = plswap(__float_as_uint(x), __float_as_uint(x));
    return fmaxf(__uint_as_float(r[0]), __uint_as_float(r[1]));
}
static __device__ __forceinline__ float xhalf_add(float x) {
    u32x2 r = plswap(__float_as_uint(x), __float_as_uint(x));
    return __uint_as_float(r[0]) + __uint_as_float(r[1]);
}

// ---------------------------------------------------------------------------
// Pass 0 (proven): K (f32 [b][k][d]) -> Kb (bf16 [b][k][d]);
//                  V (f32 [b][k][d]) -> Vtb (bf16 [b][d][k]).
// ---------------------------------------------------------------------------
__global__ __launch_bounds__(256) void fa_cvt_kernel(
    const float* __restrict__ K, const float* __restrict__ V,
    short* __restrict__ Kb, short* __restrict__ Vtb)
{
    const int tid = threadIdx.x;
    const int b   = blockIdx.y;
    const int k0  = blockIdx.x * 64;

    {
        const int kk = tid >> 2, q4 = tid & 3;
        const size_t off = ((size_t)(b * LK_ + k0 + kk)) * D_ + q4 * 16;
        const float* src = K + off;
        unsigned w[8];
#pragma unroll
        for (int i = 0; i < 4; ++i) {
            f32x4 v = *(const f32x4*)(src + 4 * i);
            w[2 * i]     = pk_bf16(v[0], v[1]);
            w[2 * i + 1] = pk_bf16(v[2], v[3]);
        }
        short* dst = Kb + off;
        *(bf16x8*)dst       = *(bf16x8*)&w[0];
        *(bf16x8*)(dst + 8) = *(bf16x8*)&w[4];
    }
    {
        const int vkg = tid & 15, vdg = tid >> 4;
        f32x4 vv[4];
#pragma unroll
        for (int p = 0; p < 4; ++p)
            vv[p] = *(const f32x4*)&V[((size_t)(b * LK_ + k0 + vkg * 4 + p)) * D_ + vdg * 4];
#pragma unroll
        for (int dr = 0; dr < 4; ++dr) {
            uint2 w = { pk_bf16(vv[0][dr], vv[1][dr]), pk_bf16(vv[2][dr], vv[3][dr]) };
            *(uint2*)&Vtb[((size_t)(b * 64 + vdg * 4 + dr)) * LK_ + k0 + vkg * 4] = w;
        }
    }
}

// ---------------------------------------------------------------------------
// Pass 1: LDS-staged split kernel, staging FROM pre-converted bf16 buffers.
// 256 threads = 4 q-waves sharing one double-buffered 64x64 K/V LDS tile.
// Writes UNNORMALIZED bf16 O^T partial + f32 (m, l) per q row.
// ---------------------------------------------------------------------------
template<int NS>
__global__ __launch_bounds__(256, 2) void fa_split12_kernel(
    const float* __restrict__ Q, const short* __restrict__ Kb,
    const short* __restrict__ Vtb, const int* __restrict__ vlen,
    short* __restrict__ OP, float* __restrict__ ML)
{
    __shared__ __align__(16) short Kl[2][64 * 64];
    __shared__ __align__(16) short Vt[2][64 * 64];

    const int tid  = threadIdx.x;          // 0..255
    const int wid  = tid >> 6;             // 0..3  (q sub-block)
    const int lane = tid & 63;
    const int c31  = lane & 31;
    const int h    = lane >> 5;

    // ---- LPT remap (LDS-free): rank batches by vl DESC, index tie-break ----
    constexpr int PB = 16 * NS;            // blocks per batch
    const int L    = blockIdx.x;
    const int rank = L / PB;
    const int sub  = L % PB;
    const int qb   = sub & 15;
    const int s    = sub >> 4;
    int b;
    {
        const int vj = vlen[c31];          // lanes j and j+32 hold vlen[j]
        int r = 0;
#pragma unroll
        for (int k = 0; k < 32; ++k) {
            const int vk = __shfl(vj, k);
            r += (vk > vj) || (vk == vj && k < c31);
        }
        const unsigned long long match = __ballot(r == rank);
        b = (int)(__ffsll(match) - 1) & 31;
    }
    const int q0 = qb * 128 + wid * 32;
    const int vl = vlen[b];
    const int nt    = (vl + 63) >> 6;
    const int chunk = (nt + NS - 1) / NS;
    const int t0    = s * chunk;
    const int t1    = min(t0 + chunk, nt);

    const float qscale = 0.125f * 1.44269504088896340736f;  // 1/sqrt(64)*log2(e)

    // ---- Q B-frags in registers: B[k=dim][n=q], dim = ks*16 + h*8 + j ----
    unsigned qfrag[4][4];
#pragma unroll
    for (int ks = 0; ks < 4; ++ks) {
        const float* qp = Q + ((size_t)(b * LQ_ + q0 + c31)) * D_ + ks * 16 + h * 8;
        f32x4 t0v = *(const f32x4*)qp;
        f32x4 t1v = *(const f32x4*)(qp + 4);
#pragma unroll
        for (int jj = 0; jj < 2; ++jj) {
            qfrag[ks][jj]     = pk_bf16(t0v[2*jj] * qscale, t0v[2*jj+1] * qscale);
            qfrag[ks][jj + 2] = pk_bf16(t1v[2*jj] * qscale, t1v[2*jj+1] * qscale);
        }
    }

    f32x16 oacc[2];     // O^T acc: dim row = dt*32 + (r&3)+8*(r>>2)+4h, col q = c31
#pragma unroll
    for (int dt = 0; dt < 2; ++dt)
#pragma unroll
        for (int r = 0; r < 16; ++r) oacc[dt][r] = 0.f;
    float mrun = -INFINITY, lrun = 0.f;

    // ---- staging maps: 256 threads x 32B each for K and V^T tiles ----
    const int skey = tid >> 2, skh = tid & 3;          // K: row, quarter
    const int vdim = skey, vkh = skh;                  // V^T: row dim, quarter

    const short* kbp = Kb  + ((size_t)(b * LK_ + skey)) * D_ + skh * 16;
    const short* vtp = Vtb + ((size_t)(b * 64 + vdim)) * LK_ + vkh * 16;

    bf16x8 kr0, kr1, vr0, vr1;
    // ---- prologue: prefetch tile t0 into registers ----
    if (t0 < t1) {
        const short* kp = kbp + (size_t)t0 * 64 * D_;
        const short* vp = vtp + (size_t)t0 * 64;
        kr0 = *(const bf16x8*)(kp);
        kr1 = *(const bf16x8*)(kp + 8);
        vr0 = *(const bf16x8*)(vp);
        vr1 = *(const bf16x8*)(vp + 8);
    }

    for (int t = t0; t < t1; ++t) {
        const int k0 = t * 64;
        const int buf = t & 1;

        // ---- write tile t to LDS (chunk c of row r at pos c^(r&7)) ----
        {
            const int pk0 = (skh * 2)     ^ (skey & 7);
            const int pk1 = (skh * 2 + 1) ^ (skey & 7);
            *(bf16x8*)&Kl[buf][skey * 64 + pk0 * 8] = kr0;
            *(bf16x8*)&Kl[buf][skey * 64 + pk1 * 8] = kr1;
            const int pv0 = (vkh * 2)     ^ (vdim & 7);
            const int pv1 = (vkh * 2 + 1) ^ (vdim & 7);
            *(bf16x8*)&Vt[buf][vdim * 64 + pv0 * 8] = vr0;
            *(bf16x8*)&Vt[buf][vdim * 64 + pv1 * 8] = vr1;
        }
        __syncthreads();

        // ---- issue prefetch for tile t+1 (flies under the compute phase) ----
        if (t + 1 < t1) {
            const short* kp = kbp + (size_t)(k0 + 64) * D_;
            const short* vp = vtp + (size_t)(k0 + 64);
            kr0 = *(const bf16x8*)(kp);
            kr1 = *(const bf16x8*)(kp + 8);
            vr0 = *(const bf16x8*)(vp);
            vr1 = *(const bf16x8*)(vp + 8);
        }

        // ---- S^T = K * Q^T : 2 key-tiles x 4 k-steps of 32x32x16 ----
        f32x16 st[2];
#pragma unroll
        for (int ss = 0; ss < 2; ++ss) {
#pragma unroll
            for (int r = 0; r < 16; ++r) st[ss][r] = 0.f;
#pragma unroll
            for (int ks = 0; ks < 4; ++ks) {
                const int pos = (ks * 2 + h) ^ (c31 & 7);
                bf16x8 kf = *(const bf16x8*)&Kl[buf][(ss * 32 + c31) * 64 + pos * 8];
                st[ss] = __builtin_amdgcn_mfma_f32_32x32x16_bf16(
                    kf, *(const bf16x8*)&qfrag[ks][0], st[ss], 0, 0, 0);
            }
        }

        // ---- mask tail keys >= vl ----
        if (k0 + 64 > vl) {
#pragma unroll
            for (int ss = 0; ss < 2; ++ss) {
                const int base = k0 + ss * 32 + 4 * h;
#pragma unroll
                for (int r = 0; r < 16; ++r) {
                    const int key = base + (r & 3) + 8 * (r >> 2);
                    if (key >= vl) st[ss][r] = -1e30f;
                }
            }
        }

        // ---- online softmax (log2 domain), defer-max; tree reductions ----
        float m8[8];
#pragma unroll
        for (int r = 0; r < 8; ++r)
            m8[r] = fmaxf(fmaxf(st[0][r], st[0][r + 8]),
                          fmaxf(st[1][r], st[1][r + 8]));
#pragma unroll
        for (int o = 4; o; o >>= 1)
#pragma unroll
            for (int r = 0; r < o; ++r) m8[r] = fmaxf(m8[r], m8[r + o]);
        const float tm = xhalf_max(m8[0]);

        if (__any(tm > mrun + 8.f)) {          // rare after the first tile
            const float mnew = fmaxf(mrun, tm);
            const float corr = exp2f(mrun - mnew);
            lrun *= corr;
#pragma unroll
            for (int dt = 0; dt < 2; ++dt)
#pragma unroll
                for (int r = 0; r < 16; ++r) oacc[dt][r] *= corr;
            mrun = mnew;
        }
#pragma unroll
        for (int ss = 0; ss < 2; ++ss)
#pragma unroll
            for (int r = 0; r < 16; ++r)
                st[ss][r] = exp2f(st[ss][r] - mrun);   // bounded by 2^8
        float s8[8];
#pragma unroll
        for (int r = 0; r < 8; ++r)
            s8[r] = (st[0][r] + st[0][r + 8]) + (st[1][r] + st[1][r + 8]);
#pragma unroll
        for (int o = 4; o; o >>= 1)
#pragma unroll
            for (int r = 0; r < o; ++r) s8[r] += s8[r + o];
        lrun += xhalf_add(s8[0]);

        // ---- pack P to bf16 pairs ----
        unsigned pk[2][8];
#pragma unroll
        for (int ss = 0; ss < 2; ++ss)
#pragma unroll
            for (int m = 0; m < 8; ++m)
                pk[ss][m] = pk_bf16(st[ss][2 * m], st[ss][2 * m + 1]);

        // ---- O^T += V^T * P^T : 4 k-steps x 2 dim-tiles ----
#pragma unroll
        for (int kq = 0; kq < 4; ++kq) {
            const int ss = kq >> 1, A4 = (kq & 1) * 4;
            u32x2 r02 = plswap(pk[ss][A4],     pk[ss][A4 + 2]);
            u32x2 r13 = plswap(pk[ss][A4 + 1], pk[ss][A4 + 3]);
            unsigned pf[4] = {r02[0], r13[0], r02[1], r13[1]};
            const bf16x8 pfr = *(const bf16x8*)&pf[0];
#pragma unroll
            for (int dt = 0; dt < 2; ++dt) {
                const int pos = (kq * 2 + h) ^ (c31 & 7);
                bf16x8 vf = *(const bf16x8*)&Vt[buf][(dt * 32 + c31) * 64 + pos * 8];
                oacc[dt] = __builtin_amdgcn_mfma_f32_32x32x16_bf16(vf, pfr, oacc[dt], 0, 0, 0);
            }
        }
    }

    // ---- epilogue: store UNNORMALIZED bf16 partial O^T and f32 (m, l) ----
    const size_t row = (size_t)s * (B_ * LQ_) + b * LQ_ + q0 + c31;
    short* op = OP + row * D_;
#pragma unroll
    for (int dt = 0; dt < 2; ++dt)
#pragma unroll
        for (int g = 0; g < 4; ++g) {
            const unsigned w0 = pk_bf16(oacc[dt][4 * g],     oacc[dt][4 * g + 1]);
            const unsigned w1 = pk_bf16(oacc[dt][4 * g + 2], oacc[dt][4 * g + 3]);
            *(uint2*)(op + dt * 32 + 8 * g + 4 * h) = uint2{w0, w1};
        }
    if (h == 0)
        *(float2*)&ML[row * 2] = float2{mrun, lrun};   // (-inf, 0) if empty split
}

// ---------------------------------------------------------------------------
// Pass 2: merge NS bf16 partials per q row. One thread per (row, 4-dim chunk).
// ---------------------------------------------------------------------------
template<int NS>
__global__ __launch_bounds__(256) void fa_merge_kernel(
    const short* __restrict__ OP, const float* __restrict__ ML,
    float* __restrict__ O)
{
    const int g   = blockIdx.x * 256 + threadIdx.x;   // 0 .. B*LQ*16-1
    const int row = g >> 4;                            // b*LQ + q
    const int qd  = (g & 15) * 4;

    float mf = -INFINITY;
#pragma unroll
    for (int s = 0; s < NS; ++s) {
        float2 ml = *(const float2*)&ML[((size_t)s * (B_ * LQ_) + row) * 2];
        mf = fmaxf(mf, ml.x);                          // split 0 always finite
    }
    float den = 0.f;
    f32x4 acc = {0.f, 0.f, 0.f, 0.f};
#pragma unroll
    for (int s = 0; s < NS; ++s) {
        const size_t srow = (size_t)s * (B_ * LQ_) + row;
        float2 ml = *(const float2*)&ML[srow * 2];
        const float c = exp2f(ml.x - mf);              // 0 for empty splits
        den += c * ml.y;
        uint2 w = *(const uint2*)&OP[srow * D_ + qd];
        acc[0] += bf_lo(w.x) * c;
        acc[1] += bf_hi(w.x) * c;
        acc[2] += bf_lo(w.y) * c;
        acc[3] += bf_hi(w.y) * c;
    }
    const float inv = 1.f / den;
    *(f32x4*)(O + (size_t)row * D_ + qd) = acc * inv;
}

// ---------------------------------------------------------------------------
// Fallback (no workspace): monolithic kernel.
// ---------------------------------------------------------------------------
__global__ __launch_bounds__(128, 2) void fa_mono_kernel(
    const float* __restrict__ Q, const float* __restrict__ K,
    const float* __restrict__ V, const int* __restrict__ vlen,
    float* __restrict__ O)
{
    __shared__ __align__(16) short Kl[2][64 * 64];
    __shared__ __align__(16) short Vt[2][64 * 64];

    const int tid  = threadIdx.x;
    const int wave = tid >> 6;
    const int lane = tid & 63;
    const int c31  = lane & 31;
    const int h    = lane >> 5;

    const int b  = blockIdx.y;
    const int q0 = blockIdx.x * 64 + wave * 32;
    const int vl = vlen[b];
    const int nt = (vl + 63) >> 6;

    const float qscale = 0.125f * 1.44269504088896340736f;

    unsigned qfrag[4][4];
#pragma unroll
    for (int ks = 0; ks < 4; ++ks) {
        const float* qp = Q + ((size_t)(b * LQ_ + q0 + c31)) * D_ + ks * 16 + h * 8;
        f32x4 t0 = *(const f32x4*)qp;
        f32x4 t1 = *(const f32x4*)(qp + 4);
#pragma unroll
        for (int jj = 0; jj < 2; ++jj) {
            qfrag[ks][jj]     = pk_bf16(t0[2*jj] * qscale, t0[2*jj+1] * qscale);
            qfrag[ks][jj + 2] = pk_bf16(t1[2*jj] * qscale, t1[2*jj+1] * qscale);
        }
    }

    f32x16 oacc[2];
#pragma unroll
    for (int dt = 0; dt < 2; ++dt)
#pragma unroll
        for (int r = 0; r < 16; ++r) oacc[dt][r] = 0.f;
    float mrun = -INFINITY, lrun = 0.f;

    const int skey = tid >> 1, skh = tid & 1;
    const int vkg = tid >> 4, vdg = tid & 15;

    const float* kgp = K + ((size_t)(b * LK_ + skey)) * D_ + skh * 32;
    const float* vgp = V + ((size_t)(b * LK_ + vkg * 8)) * D_ + vdg * 4;

    f32x4 kr[8], vr[8];
#pragma unroll
    for (int i = 0; i < 8; ++i) kr[i] = *(const f32x4*)(kgp + 4 * i);
#pragma unroll
    for (int i = 0; i < 8; ++i) vr[i] = *(const f32x4*)(vgp + (size_t)i * D_);

    for (int t = 0; t < nt; ++t) {
        const int k0 = t * 64;
        const int buf = t & 1;
        {
            unsigned pk32[16];
#pragma unroll
            for (int m = 0; m < 16; ++m)
                pk32[m] = pk_bf16(kr[m >> 1][2 * (m & 1)], kr[m >> 1][2 * (m & 1) + 1]);
#pragma unroll
            for (int cch = 0; cch < 4; ++cch) {
                const int pos = (skh * 4 + cch) ^ (skey & 7);
                *(bf16x8*)&Kl[buf][skey * 64 + pos * 8] = *(bf16x8*)&pk32[4 * cch];
            }
#pragma unroll
            for (int dr = 0; dr < 4; ++dr) {
                unsigned w[4];
#pragma unroll
                for (int p = 0; p < 4; ++p)
                    w[p] = pk_bf16(vr[2 * p][dr], vr[2 * p + 1][dr]);
                const int dim = vdg * 4 + dr;
                const int pos = vkg ^ (dim & 7);
                *(bf16x8*)&Vt[buf][dim * 64 + pos * 8] = *(bf16x8*)&w[0];
            }
        }
        if (t + 1 < nt) {
            const float* kn = kgp + (size_t)(k0 + 64) * D_;
            const float* vn = vgp + (size_t)(k0 + 64) * D_;
#pragma unroll
            for (int i = 0; i < 8; ++i) kr[i] = *(const f32x4*)(kn + 4 * i);
#pragma unroll
            for (int i = 0; i < 8; ++i) vr[i] = *(const f32x4*)(vn + (size_t)i * D_);
        }
        __syncthreads();

        f32x16 st[2];
#pragma unroll
        for (int ss = 0; ss < 2; ++ss) {
#pragma unroll
            for (int r = 0; r < 16; ++r) st[ss][r] = 0.f;
#pragma unroll
            for (int ks = 0; ks < 4; ++ks) {
                const int pos = (ks * 2 + h) ^ (c31 & 7);
                bf16x8 kf = *(const bf16x8*)&Kl[buf][(ss * 32 + c31) * 64 + pos * 8];
                st[ss] = __builtin_amdgcn_mfma_f32_32x32x16_bf16(
                    kf, *(const bf16x8*)&qfrag[ks][0], st[ss], 0, 0, 0);
            }
        }
        if (k0 + 64 > vl) {
#pragma unroll
            for (int ss = 0; ss < 2; ++ss) {
                const int base = k0 + ss * 32 + 4 * h;
#pragma unroll
                for (int r = 0; r < 16; ++r) {
                    const int key = base + (r & 3) + 8 * (r >> 2);
                    if (key >= vl) st[ss][r] = -1e30f;
                }
            }
        }
        float tm = st[0][0];
#pragma unroll
        for (int ss = 0; ss < 2; ++ss)
#pragma unroll
            for (int r = 0; r < 16; ++r) tm = fmaxf(tm, st[ss][r]);
        tm = fmaxf(tm, __shfl_xor(tm, 32));
        if (__any(tm > mrun + 8.f)) {
            const float mnew = fmaxf(mrun, tm);
            const float corr = exp2f(mrun - mnew);
            lrun *= corr;
#pragma unroll
            for (int dt = 0; dt < 2; ++dt)
#pragma unroll
                for (int r = 0; r < 16; ++r) oacc[dt][r] *= corr;
            mrun = mnew;
        }
        float rs = 0.f;
#pragma unroll
        for (int ss = 0; ss < 2; ++ss)
#pragma unroll
            for (int r = 0; r < 16; ++r) {
                const float p = exp2f(st[ss][r] - mrun);
                st[ss][r] = p;
                rs += p;
            }
        rs += __shfl_xor(rs, 32);
        lrun += rs;

        unsigned pk[2][8];
#pragma unroll
        for (int ss = 0; ss < 2; ++ss)
#pragma unroll
            for (int m = 0; m < 8; ++m)
                pk[ss][m] = pk_bf16(st[ss][2 * m], st[ss][2 * m + 1]);
#pragma unroll
        for (int kq = 0; kq < 4; ++kq) {
            const int ss = kq >> 1, A4 = (kq & 1) * 4;
            unsigned p0 = pk[ss][A4], p1 = pk[ss][A4+1], p2 = pk[ss][A4+2], p3 = pk[ss][A4+3];
            unsigned xp0 = __shfl_xor((int)p0, 32);
            unsigned xp1 = __shfl_xor((int)p1, 32);
            unsigned xp2 = __shfl_xor((int)p2, 32);
            unsigned xp3 = __shfl_xor((int)p3, 32);
            unsigned pf[4];
            pf[0] = h ? xp2 : p0;
            pf[1] = h ? xp3 : p1;
            pf[2] = h ? p2  : xp0;
            pf[3] = h ? p3  : xp1;
            const bf16x8 pfr = *(const bf16x8*)&pf[0];
#pragma unroll
            for (int dt = 0; dt < 2; ++dt) {
                const int pos = (kq * 2 + h) ^ (c31 & 7);
                bf16x8 vf = *(const bf16x8*)&Vt[buf][(dt * 32 + c31) * 64 + pos * 8];
                oacc[dt] = __builtin_amdgcn_mfma_f32_32x32x16_bf16(vf, pfr, oacc[dt], 0, 0, 0);
            }
        }
    }

    const float inv = 1.f / lrun;
    float* op = O + ((size_t)(b * LQ_ + q0 + c31)) * D_;
#pragma unroll
    for (int dt = 0; dt < 2; ++dt)
#pragma unroll
        for (int g = 0; g < 4; ++g) {
            f32x4 v;
#pragma unroll
            for (int j = 0; j < 4; ++j) v[j] = oacc[dt][4 * g + j] * inv;
            *(f32x4*)(op + dt * 32 + 8 * g + 4 * h) = v;
        }
}

extern "C" void kernel_launch(void* const* d_in, const int* in_sizes, int n_in,
                              void* d_out, int out_size, void* d_ws, size_t ws_size,
                              hipStream_t stream) {
    const float* Q    = (const float*)d_in[0];
    const float* K    = (const float*)d_in[1];
    const float* V    = (const float*)d_in[2];
    const int*   vlen = (const int*)d_in[3];
    float*       O    = (float*)d_out;

    const size_t rows    = (size_t)B_ * LQ_;
    const size_t kvElems = (size_t)B_ * LK_ * D_;          // per tensor
    constexpr int NS = 4;
    // OP: NS*rows*D bf16 (16.8MB); ML: NS*rows*2 f32 (2.1MB); Kb+Vtb: 33.6MB
    const size_t opBytes = (size_t)NS * rows * D_ * sizeof(short);
    const size_t mlBytes = (size_t)NS * rows * 2 * sizeof(float);
    const size_t kvBytes = 2 * kvElems * sizeof(short);
    const size_t needAll = opBytes + mlBytes + kvBytes;

    if (d_ws && ws_size >= needAll) {
        short* OP  = (short*)d_ws;
        float* ML  = (float*)((char*)d_ws + opBytes);
        short* Kb  = (short*)((char*)d_ws + opBytes + mlBytes);
        short* Vtb = Kb + kvElems;

        fa_cvt_kernel<<<dim3(LK_ / 64, B_), dim3(256), 0, stream>>>(K, V, Kb, Vtb);

        const unsigned nblk = (unsigned)(16 * B_ * NS);
        fa_split12_kernel<NS><<<dim3(nblk), dim3(256), 0, stream>>>(Q, Kb, Vtb, vlen, OP, ML);

        dim3 g2((unsigned)((rows * (D_ / 4)) / 256));
        fa_merge_kernel<NS><<<g2, dim3(256), 0, stream>>>(OP, ML, O);
        return;
    }

    dim3 grid(LQ_ / 64, B_);
    fa_mono_kernel<<<grid, dim3(128), 0, stream>>>(Q, K, V, vlen, O);
}